// Round 2
// baseline (3744.208 us; speedup 1.0000x reference)
//
#include <hip/hip_runtime.h>
#include <hip/hip_bf16.h>

#define HID 128
#define FDIM 133

typedef __hip_bfloat16 bf16;

__device__ __forceinline__ float b2f(bf16 v) { return __bfloat162float(v); }
__device__ __forceinline__ bf16 f2b(float v) { return __float2bfloat16(v); }
__device__ __forceinline__ unsigned short bbits(float v) {
    union { bf16 b; unsigned short u; } cv; cv.b = __float2bfloat16(v); return cv.u;
}
__device__ __forceinline__ float lo16(unsigned u) { return __uint_as_float(u << 16); }
__device__ __forceinline__ float hi16(unsigned u) { return __uint_as_float(u & 0xffff0000u); }

__global__ void k_zero(float* __restrict__ p, long long n) {
    long long i = (long long)blockIdx.x * blockDim.x + threadIdx.x;
    long long st = (long long)gridDim.x * blockDim.x;
    for (; i < n; i += st) p[i] = 0.f;
}

// h[e][j] = relu(sum_k W1[j][k]*[x[src[e]],eattr[e]][k]); optionally copy to h0
__global__ void k_h0(const float* __restrict__ x, const int* __restrict__ src,
                     const float* __restrict__ eattr, const float* __restrict__ W1,
                     bf16* __restrict__ h, bf16* __restrict__ h0cpy, int E) {
    __shared__ uint2 w[34 * HID];                 // w[kq*128+j] = W1[j][4kq..4kq+3] bf16x4
    __shared__ __align__(16) float msg[2][136];
    const int tid = threadIdx.x, sub = tid >> 7, j = tid & 127;
    for (int idx = tid; idx < 34 * HID; idx += 256) {
        int kq = idx >> 7, jj = idx & 127, k = 4 * kq;
        float v0 = (k + 0 < 134) ? W1[jj * 134 + k + 0] : 0.f;
        float v1 = (k + 1 < 134) ? W1[jj * 134 + k + 1] : 0.f;
        float v2 = (k + 2 < 134) ? W1[jj * 134 + k + 2] : 0.f;
        float v3 = (k + 3 < 134) ? W1[jj * 134 + k + 3] : 0.f;
        w[idx] = make_uint2((unsigned)bbits(v0) | ((unsigned)bbits(v1) << 16),
                            (unsigned)bbits(v2) | ((unsigned)bbits(v3) << 16));
    }
    if (tid < 4) msg[tid >> 1][134 + (tid & 1)] = 0.f;
    __syncthreads();
    int g = gridDim.x;
    int per = (E / 2 + g - 1) / g;
    int ps = blockIdx.x * per, pe = min(ps + per, E / 2);
    for (int p = ps; p < pe; ++p) {
        int e = 2 * p + sub;
        int sn = src[e];
        const float* xr = x + (size_t)sn * FDIM;
        msg[sub][j] = xr[j];
        if (j < 6) { int k2 = 128 + j; msg[sub][k2] = (k2 < FDIM) ? xr[k2] : eattr[e]; }
        __syncthreads();
        float acc = 0.f;
#pragma unroll
        for (int kq = 0; kq < 34; ++kq) {
            uint2 u = w[kq * HID + j];
            float4 mv = *reinterpret_cast<const float4*>(&msg[sub][4 * kq]);
            acc += lo16(u.x) * mv.x + hi16(u.x) * mv.y + lo16(u.y) * mv.z + hi16(u.y) * mv.w;
        }
        bf16 o = f2b(fmaxf(acc, 0.f));
        size_t off = (size_t)e * HID + j;
        h[off] = o;
        if (h0cpy) h0cpy[off] = o;
        __syncthreads();
    }
}

// acc[dst[e]] += h[e]  (fp32 atomics, 4 channels/thread)
__global__ void k_segsum(const bf16* __restrict__ h, const int* __restrict__ dst,
                         float* __restrict__ acc, int E) {
    int idx = blockIdx.x * blockDim.x + threadIdx.x;
    if (idx >= E * 32) return;
    int e = idx >> 5, q = idx & 31;
    int d = dst[e];
    const uint2 v = *reinterpret_cast<const uint2*>(h + (size_t)e * HID + q * 4);
    float* ap = acc + (size_t)d * HID + q * 4;
    atomicAdd(ap + 0, __uint_as_float(v.x << 16));
    atomicAdd(ap + 1, __uint_as_float(v.x & 0xffff0000u));
    atomicAdd(ap + 2, __uint_as_float(v.y << 16));
    atomicAdd(ap + 3, __uint_as_float(v.y & 0xffff0000u));
}

// In-place: h[e] = relu(h0[e] + W2*(mnode[src[e]] - h[e^1])) per edge-pair.
// USE_H0=false recomputes h0 from x/W1/eattr (needs W1+W2 in LDS, ~70 KB dynamic).
template <bool USE_H0>
__global__ void k_update(const int* __restrict__ src, const float* __restrict__ x,
                         const float* __restrict__ eattr, const float* __restrict__ mnode,
                         const bf16* __restrict__ h0, bf16* __restrict__ h,
                         const float* __restrict__ W1, const float* __restrict__ W2, int E) {
    extern __shared__ char smem[];
    uint2* w2 = (uint2*)smem;                                  // 32*128 uint2 = 32768 B
    float* m = (float*)(smem + 32768);                         // [2][136]  = 1088 B
    uint2* w1 = (uint2*)(smem + 32768 + 1088);                 // 34*128 uint2 = 34816 B
    float* xm = (float*)(smem + 32768 + 1088 + 34816);         // [2][136]  = 1088 B
    const int tid = threadIdx.x, sub = tid >> 7, j = tid & 127;
    for (int idx = tid; idx < 32 * HID; idx += 256) {
        int kq = idx >> 7, jj = idx & 127, k = 4 * kq;
        w2[idx] = make_uint2(
            (unsigned)bbits(W2[jj * HID + k + 0]) | ((unsigned)bbits(W2[jj * HID + k + 1]) << 16),
            (unsigned)bbits(W2[jj * HID + k + 2]) | ((unsigned)bbits(W2[jj * HID + k + 3]) << 16));
    }
    if (!USE_H0) {
        for (int idx = tid; idx < 34 * HID; idx += 256) {
            int kq = idx >> 7, jj = idx & 127, k = 4 * kq;
            float v0 = (k + 0 < 134) ? W1[jj * 134 + k + 0] : 0.f;
            float v1 = (k + 1 < 134) ? W1[jj * 134 + k + 1] : 0.f;
            float v2 = (k + 2 < 134) ? W1[jj * 134 + k + 2] : 0.f;
            float v3 = (k + 3 < 134) ? W1[jj * 134 + k + 3] : 0.f;
            w1[idx] = make_uint2((unsigned)bbits(v0) | ((unsigned)bbits(v1) << 16),
                                 (unsigned)bbits(v2) | ((unsigned)bbits(v3) << 16));
        }
        if (tid < 4) xm[(tid >> 1) * 136 + 134 + (tid & 1)] = 0.f;
    }
    __syncthreads();
    int g = gridDim.x;
    int per = (E / 2 + g - 1) / g;
    int ps = blockIdx.x * per, pe = min(ps + per, E / 2);
    for (int p = ps; p < pe; ++p) {
        int e = 2 * p + sub, er = 2 * p + (1 - sub);
        int sn = src[e];
        m[sub * 136 + j] = mnode[(size_t)sn * HID + j] - b2f(h[(size_t)er * HID + j]);
        if (!USE_H0) {
            const float* xr = x + (size_t)sn * FDIM;
            xm[sub * 136 + j] = xr[j];
            if (j < 6) { int k2 = 128 + j; xm[sub * 136 + k2] = (k2 < FDIM) ? xr[k2] : eattr[e]; }
        }
        __syncthreads();
        float h0v;
        if (USE_H0) {
            h0v = b2f(h0[(size_t)e * HID + j]);
        } else {
            float a = 0.f;
#pragma unroll
            for (int kq = 0; kq < 34; ++kq) {
                uint2 u = w1[kq * HID + j];
                float4 mv = *reinterpret_cast<const float4*>(&xm[sub * 136 + 4 * kq]);
                a += lo16(u.x) * mv.x + hi16(u.x) * mv.y + lo16(u.y) * mv.z + hi16(u.y) * mv.w;
            }
            h0v = fmaxf(a, 0.f);
        }
        float acc = h0v;
#pragma unroll
        for (int kq = 0; kq < 32; ++kq) {
            uint2 u = w2[kq * HID + j];
            float4 mv = *reinterpret_cast<const float4*>(&m[sub * 136 + 4 * kq]);
            acc += lo16(u.x) * mv.x + hi16(u.x) * mv.y + lo16(u.y) * mv.z + hi16(u.y) * mv.w;
        }
        h[(size_t)e * HID + j] = f2b(fmaxf(acc, 0.f));
        __syncthreads();
    }
}

// node MLP + fused mean-pool accumulation
__global__ void k_node(const float* __restrict__ x, const float* __restrict__ vmsg,
                       const float* __restrict__ W3, const float* __restrict__ b3,
                       const int* __restrict__ batch, float* __restrict__ sums,
                       float* __restrict__ counts, int N) {
    __shared__ uint2 w[66 * 64];                  // w[kq*64+jj] = W3[half*64+jj][4kq..] bf16x4
    __shared__ __align__(16) float z[4][264];
    const int tid = threadIdx.x, sub = tid >> 6, j64 = tid & 63;
    const int half = blockIdx.y;
    for (int idx = tid; idx < 66 * 64; idx += 256) {
        int kq = idx >> 6, jj = idx & 63, k = 4 * kq;
        const float* wr = W3 + (size_t)(half * 64 + jj) * 261;
        float v0 = (k + 0 < 261) ? wr[k + 0] : 0.f;
        float v1 = (k + 1 < 261) ? wr[k + 1] : 0.f;
        float v2 = (k + 2 < 261) ? wr[k + 2] : 0.f;
        float v3 = (k + 3 < 261) ? wr[k + 3] : 0.f;
        w[idx] = make_uint2((unsigned)bbits(v0) | ((unsigned)bbits(v1) << 16),
                            (unsigned)bbits(v2) | ((unsigned)bbits(v3) << 16));
    }
    if (tid < 12) { int r = tid / 3, c = tid % 3; z[r][261 + c] = 0.f; }
    __syncthreads();
    const int j = half * 64 + j64;
    const float bj = b3[j];
    int g = gridDim.x;
    int per = ((N + 4 * g - 1) / (4 * g)) * 4;
    int s = blockIdx.x * per, nend = min(s + per, N);
    for (int n0 = s; n0 < nend; n0 += 4) {
        int n = n0 + sub;
        bool act = n < nend;
        if (act) {
            const float* xr = x + (size_t)n * FDIM;
            const float* vr = vmsg + (size_t)n * HID;
            for (int k = j64; k < 261; k += 64) z[sub][k] = (k < FDIM) ? xr[k] : vr[k - FDIM];
        }
        __syncthreads();
        if (act) {
            float acc = bj;
#pragma unroll
            for (int kq = 0; kq < 66; ++kq) {
                uint2 u = w[kq * 64 + j64];
                float4 zv = *reinterpret_cast<const float4*>(&z[sub][4 * kq]);
                acc += lo16(u.x) * zv.x + hi16(u.x) * zv.y + lo16(u.y) * zv.z + hi16(u.y) * zv.w;
            }
            int gg = batch[n];
            atomicAdd(&sums[(size_t)gg * HID + j], fmaxf(acc, 0.f));
            if (half == 0 && j64 == 0) atomicAdd(&counts[gg], 1.0f);
        }
        __syncthreads();
    }
}

__global__ void k_out(const float* __restrict__ sums, const float* __restrict__ counts,
                      const float* __restrict__ Wfc, const float* __restrict__ bfc,
                      float* __restrict__ out, int G) {
    __shared__ float pooled[HID];
    const int g = blockIdx.x, tid = threadIdx.x;  // 64 threads
    float inv = 1.0f / fmaxf(counts[g], 1.0f);
    pooled[tid] = sums[(size_t)g * HID + tid] * inv;
    pooled[tid + 64] = sums[(size_t)g * HID + tid + 64] * inv;
    __syncthreads();
    float acc = bfc[tid];
#pragma unroll
    for (int k = 0; k < HID; ++k) acc += Wfc[tid * HID + k] * pooled[k];
    out[(size_t)g * 64 + tid] = tanhf(acc);
}

extern "C" void kernel_launch(void* const* d_in, const int* in_sizes, int n_in,
                              void* d_out, int out_size, void* d_ws, size_t ws_size,
                              hipStream_t stream) {
    const float* x     = (const float*)d_in[0];
    const int*   ei    = (const int*)d_in[1];
    const float* eattr = (const float*)d_in[3];
    const int*   batch = (const int*)d_in[4];
    const float* W1    = (const float*)d_in[6];
    const float* W2    = (const float*)d_in[7];
    const float* W3    = (const float*)d_in[8];
    const float* b3    = (const float*)d_in[9];
    const float* Wfc   = (const float*)d_in[10];
    const float* bfc   = (const float*)d_in[11];
    float* out = (float*)d_out;
    (void)n_in;

    const int N = in_sizes[0] / FDIM;
    const int E = in_sizes[3];
    const int G = out_size / 64;
    const int* src = ei;
    const int* dst = ei + E;

    char* ws = (char*)d_ws;
    size_t sz_h = (size_t)E * HID * sizeof(bf16);
    size_t o_m = sz_h,            sz_m = (size_t)N * HID * sizeof(float);
    size_t o_s = o_m + sz_m,      sz_s = (size_t)G * HID * sizeof(float);
    size_t o_c = o_s + sz_s,      sz_c = (size_t)G * sizeof(float);
    size_t o_h0 = ((o_c + sz_c) + 255) & ~(size_t)255;
    bool useH0 = ws_size >= o_h0 + sz_h;

    bf16* h      = (bf16*)ws;
    float* mnode = (float*)(ws + o_m);
    float* sums  = (float*)(ws + o_s);
    float* counts= (float*)(ws + o_c);
    bf16* h0     = (bf16*)(ws + o_h0);

    const int SM_A = 32768 + 1088;                 // W2 + m
    const int SM_B = 32768 + 1088 + 34816 + 1088;  // + W1 + xm
    if (!useH0) {
        hipFuncSetAttribute(reinterpret_cast<const void*>(k_update<false>),
                            hipFuncAttributeMaxDynamicSharedMemorySize, SM_B);
    }

    const int segGrid = (E * 32 + 255) / 256;

    // zero mnode|sums|counts (contiguous)
    k_zero<<<1024, 256, 0, stream>>>(mnode, (long long)N * HID + (long long)G * HID + G);

    k_h0<<<2048, 256, 0, stream>>>(x, src, eattr, W1, h, useH0 ? h0 : (bf16*)nullptr, E);

    // iter 1
    k_segsum<<<segGrid, 256, 0, stream>>>(h, dst, mnode, E);
    if (useH0) k_update<true><<<2048, 256, SM_A, stream>>>(src, x, eattr, mnode, h0, h, W1, W2, E);
    else       k_update<false><<<2048, 256, SM_B, stream>>>(src, x, eattr, mnode, nullptr, h, W1, W2, E);

    // iter 2
    k_zero<<<1024, 256, 0, stream>>>(mnode, (long long)N * HID);
    k_segsum<<<segGrid, 256, 0, stream>>>(h, dst, mnode, E);
    if (useH0) k_update<true><<<2048, 256, SM_A, stream>>>(src, x, eattr, mnode, h0, h, W1, W2, E);
    else       k_update<false><<<2048, 256, SM_B, stream>>>(src, x, eattr, mnode, nullptr, h, W1, W2, E);

    // final v_msg
    k_zero<<<1024, 256, 0, stream>>>(mnode, (long long)N * HID);
    k_segsum<<<segGrid, 256, 0, stream>>>(h, dst, mnode, E);

    k_node<<<dim3(1024, 2), 256, 0, stream>>>(x, mnode, W3, b3, batch, sums, counts, N);
    k_out<<<G, 64, 0, stream>>>(sums, counts, Wfc, bfc, out, G);
}

// Round 3
// 1884.707 us; speedup vs baseline: 1.9866x; 1.9866x over previous
//
#include <hip/hip_runtime.h>
#include <hip/hip_bf16.h>

#define HID 128
#define FDIM 133

typedef __hip_bfloat16 bf16;

__device__ __forceinline__ float b2f(bf16 v) { return __bfloat162float(v); }
__device__ __forceinline__ bf16 f2b(float v) { return __float2bfloat16(v); }
__device__ __forceinline__ unsigned short bbits(float v) {
    union { bf16 b; unsigned short u; } cv; cv.b = __float2bfloat16(v); return cv.u;
}
__device__ __forceinline__ float lo16(unsigned u) { return __uint_as_float(u << 16); }
__device__ __forceinline__ float hi16(unsigned u) { return __uint_as_float(u & 0xffff0000u); }

__global__ void k_zero(float* __restrict__ p, long long n) {
    long long i = (long long)blockIdx.x * blockDim.x + threadIdx.x;
    long long st = (long long)gridDim.x * blockDim.x;
    for (; i < n; i += st) p[i] = 0.f;
}

// ---------------- CSR build (incoming edges per dst) ----------------
__global__ void k_hist(const int* __restrict__ dst, int* __restrict__ deg, int E) {
    int i = blockIdx.x * blockDim.x + threadIdx.x;
    if (i < E) atomicAdd(&deg[dst[i]], 1);
}

// 1024 elems / block (256 thr x 4): exclusive scan within block + block total
__global__ void k_scanA(const int* __restrict__ deg, int* __restrict__ offs,
                        int* __restrict__ bsum, int N) {
    __shared__ int sh[256];
    int t = threadIdx.x;
    int base = blockIdx.x * 1024 + t * 4;
    int d0 = (base + 0 < N) ? deg[base + 0] : 0;
    int d1 = (base + 1 < N) ? deg[base + 1] : 0;
    int d2 = (base + 2 < N) ? deg[base + 2] : 0;
    int d3 = (base + 3 < N) ? deg[base + 3] : 0;
    sh[t] = d0 + d1 + d2 + d3;
    __syncthreads();
    for (int off = 1; off < 256; off <<= 1) {
        int v = (t >= off) ? sh[t - off] : 0;
        __syncthreads();
        sh[t] += v;
        __syncthreads();
    }
    int o = (t > 0) ? sh[t - 1] : 0;
    if (t == 255) bsum[blockIdx.x] = sh[255];
    if (base + 0 < N) offs[base + 0] = o; o += d0;
    if (base + 1 < N) offs[base + 1] = o; o += d1;
    if (base + 2 < N) offs[base + 2] = o; o += d2;
    if (base + 3 < N) offs[base + 3] = o;
}

// single-block exclusive scan of block sums (nb <= 256)
__global__ void k_scanB(int* __restrict__ bsum, int nb) {
    __shared__ int sh[256];
    int t = threadIdx.x;
    sh[t] = (t < nb) ? bsum[t] : 0;
    __syncthreads();
    for (int off = 1; off < 256; off <<= 1) {
        int v = (t >= off) ? sh[t - off] : 0;
        __syncthreads();
        sh[t] += v;
        __syncthreads();
    }
    if (t < nb) bsum[t] = (t > 0) ? sh[t - 1] : 0;
}

__global__ void k_scanC(int* __restrict__ offs, const int* __restrict__ bsum, int N) {
    int i = blockIdx.x * blockDim.x + threadIdx.x;
    if (i < N) offs[i] += bsum[i >> 10];
}

__global__ void k_fill(const int* __restrict__ dst, const int* __restrict__ offs,
                       int* __restrict__ cursor, int* __restrict__ csr, int E) {
    int e = blockIdx.x * blockDim.x + threadIdx.x;
    if (e < E) {
        int d = dst[e];
        int p = offs[d] + atomicAdd(&cursor[d], 1);
        csr[p] = e;
    }
}

// mnode[n] = sum of h rows over incoming edges (one wave per node)
__global__ void k_gather(const bf16* __restrict__ h, const int* __restrict__ csr,
                         const int* __restrict__ offs, const int* __restrict__ deg,
                         float* __restrict__ mnode, int N) {
    int gw = (blockIdx.x * blockDim.x + threadIdx.x) >> 6;
    int lane = threadIdx.x & 63;
    int nw = (gridDim.x * blockDim.x) >> 6;
    for (int n = gw; n < N; n += nw) {
        int s = offs[n], d = deg[n];
        float a0 = 0.f, a1 = 0.f;
        for (int i = 0; i < d; ++i) {
            int e = csr[s + i];
            unsigned u = *reinterpret_cast<const unsigned*>(h + (size_t)e * HID + 2 * lane);
            a0 += lo16(u);
            a1 += hi16(u);
        }
        *reinterpret_cast<float2*>(mnode + (size_t)n * HID + 2 * lane) = make_float2(a0, a1);
    }
}

// ---------------- edge / node GEMM kernels ----------------
// h[e][j] = relu(sum_k W1[j][k]*[x[src[e]],eattr[e]][k]); optionally copy to h0
__global__ void k_h0(const float* __restrict__ x, const int* __restrict__ src,
                     const float* __restrict__ eattr, const float* __restrict__ W1,
                     bf16* __restrict__ h, bf16* __restrict__ h0cpy, int E) {
    __shared__ uint2 w[34 * HID];
    __shared__ __align__(16) float msg[2][136];
    const int tid = threadIdx.x, sub = tid >> 7, j = tid & 127;
    for (int idx = tid; idx < 34 * HID; idx += 256) {
        int kq = idx >> 7, jj = idx & 127, k = 4 * kq;
        float v0 = (k + 0 < 134) ? W1[jj * 134 + k + 0] : 0.f;
        float v1 = (k + 1 < 134) ? W1[jj * 134 + k + 1] : 0.f;
        float v2 = (k + 2 < 134) ? W1[jj * 134 + k + 2] : 0.f;
        float v3 = (k + 3 < 134) ? W1[jj * 134 + k + 3] : 0.f;
        w[idx] = make_uint2((unsigned)bbits(v0) | ((unsigned)bbits(v1) << 16),
                            (unsigned)bbits(v2) | ((unsigned)bbits(v3) << 16));
    }
    if (tid < 4) msg[tid >> 1][134 + (tid & 1)] = 0.f;
    __syncthreads();
    int g = gridDim.x;
    int per = (E / 2 + g - 1) / g;
    int ps = blockIdx.x * per, pe = min(ps + per, E / 2);
    for (int p = ps; p < pe; ++p) {
        int e = 2 * p + sub;
        int sn = src[e];
        const float* xr = x + (size_t)sn * FDIM;
        msg[sub][j] = xr[j];
        if (j < 6) { int k2 = 128 + j; msg[sub][k2] = (k2 < FDIM) ? xr[k2] : eattr[e]; }
        __syncthreads();
        float acc = 0.f;
#pragma unroll
        for (int kq = 0; kq < 34; ++kq) {
            uint2 u = w[kq * HID + j];
            float4 mv = *reinterpret_cast<const float4*>(&msg[sub][4 * kq]);
            acc += lo16(u.x) * mv.x + hi16(u.x) * mv.y + lo16(u.y) * mv.z + hi16(u.y) * mv.w;
        }
        bf16 o = f2b(fmaxf(acc, 0.f));
        size_t off = (size_t)e * HID + j;
        h[off] = o;
        if (h0cpy) h0cpy[off] = o;
        __syncthreads();
    }
}

// In-place: h[e] = relu(h0[e] + W2*(mnode[src[e]] - h[e^1])) per edge-pair.
template <bool USE_H0>
__global__ void k_update(const int* __restrict__ src, const float* __restrict__ x,
                         const float* __restrict__ eattr, const float* __restrict__ mnode,
                         const bf16* __restrict__ h0, bf16* __restrict__ h,
                         const float* __restrict__ W1, const float* __restrict__ W2, int E) {
    extern __shared__ char smem[];
    uint2* w2 = (uint2*)smem;
    float* m = (float*)(smem + 32768);
    uint2* w1 = (uint2*)(smem + 32768 + 1088);
    float* xm = (float*)(smem + 32768 + 1088 + 34816);
    const int tid = threadIdx.x, sub = tid >> 7, j = tid & 127;
    for (int idx = tid; idx < 32 * HID; idx += 256) {
        int kq = idx >> 7, jj = idx & 127, k = 4 * kq;
        w2[idx] = make_uint2(
            (unsigned)bbits(W2[jj * HID + k + 0]) | ((unsigned)bbits(W2[jj * HID + k + 1]) << 16),
            (unsigned)bbits(W2[jj * HID + k + 2]) | ((unsigned)bbits(W2[jj * HID + k + 3]) << 16));
    }
    if (!USE_H0) {
        for (int idx = tid; idx < 34 * HID; idx += 256) {
            int kq = idx >> 7, jj = idx & 127, k = 4 * kq;
            float v0 = (k + 0 < 134) ? W1[jj * 134 + k + 0] : 0.f;
            float v1 = (k + 1 < 134) ? W1[jj * 134 + k + 1] : 0.f;
            float v2 = (k + 2 < 134) ? W1[jj * 134 + k + 2] : 0.f;
            float v3 = (k + 3 < 134) ? W1[jj * 134 + k + 3] : 0.f;
            w1[idx] = make_uint2((unsigned)bbits(v0) | ((unsigned)bbits(v1) << 16),
                                 (unsigned)bbits(v2) | ((unsigned)bbits(v3) << 16));
        }
        if (tid < 4) xm[(tid >> 1) * 136 + 134 + (tid & 1)] = 0.f;
    }
    __syncthreads();
    int g = gridDim.x;
    int per = (E / 2 + g - 1) / g;
    int ps = blockIdx.x * per, pe = min(ps + per, E / 2);
    for (int p = ps; p < pe; ++p) {
        int e = 2 * p + sub, er = 2 * p + (1 - sub);
        int sn = src[e];
        m[sub * 136 + j] = mnode[(size_t)sn * HID + j] - b2f(h[(size_t)er * HID + j]);
        if (!USE_H0) {
            const float* xr = x + (size_t)sn * FDIM;
            xm[sub * 136 + j] = xr[j];
            if (j < 6) { int k2 = 128 + j; xm[sub * 136 + k2] = (k2 < FDIM) ? xr[k2] : eattr[e]; }
        }
        __syncthreads();
        float h0v;
        if (USE_H0) {
            h0v = b2f(h0[(size_t)e * HID + j]);
        } else {
            float a = 0.f;
#pragma unroll
            for (int kq = 0; kq < 34; ++kq) {
                uint2 u = w1[kq * HID + j];
                float4 mv = *reinterpret_cast<const float4*>(&xm[sub * 136 + 4 * kq]);
                a += lo16(u.x) * mv.x + hi16(u.x) * mv.y + lo16(u.y) * mv.z + hi16(u.y) * mv.w;
            }
            h0v = fmaxf(a, 0.f);
        }
        float acc = h0v;
#pragma unroll
        for (int kq = 0; kq < 32; ++kq) {
            uint2 u = w2[kq * HID + j];
            float4 mv = *reinterpret_cast<const float4*>(&m[sub * 136 + 4 * kq]);
            acc += lo16(u.x) * mv.x + hi16(u.x) * mv.y + lo16(u.y) * mv.z + hi16(u.y) * mv.w;
        }
        h[(size_t)e * HID + j] = f2b(fmaxf(acc, 0.f));
        __syncthreads();
    }
}

// node MLP + fused mean-pool accumulation
__global__ void k_node(const float* __restrict__ x, const float* __restrict__ vmsg,
                       const float* __restrict__ W3, const float* __restrict__ b3,
                       const int* __restrict__ batch, float* __restrict__ sums,
                       float* __restrict__ counts, int N) {
    __shared__ uint2 w[66 * 64];
    __shared__ __align__(16) float z[4][264];
    const int tid = threadIdx.x, sub = tid >> 6, j64 = tid & 63;
    const int half = blockIdx.y;
    for (int idx = tid; idx < 66 * 64; idx += 256) {
        int kq = idx >> 6, jj = idx & 63, k = 4 * kq;
        const float* wr = W3 + (size_t)(half * 64 + jj) * 261;
        float v0 = (k + 0 < 261) ? wr[k + 0] : 0.f;
        float v1 = (k + 1 < 261) ? wr[k + 1] : 0.f;
        float v2 = (k + 2 < 261) ? wr[k + 2] : 0.f;
        float v3 = (k + 3 < 261) ? wr[k + 3] : 0.f;
        w[idx] = make_uint2((unsigned)bbits(v0) | ((unsigned)bbits(v1) << 16),
                            (unsigned)bbits(v2) | ((unsigned)bbits(v3) << 16));
    }
    if (tid < 12) { int r = tid / 3, c = tid % 3; z[r][261 + c] = 0.f; }
    __syncthreads();
    const int j = half * 64 + j64;
    const float bj = b3[j];
    int g = gridDim.x;
    int per = ((N + 4 * g - 1) / (4 * g)) * 4;
    int s = blockIdx.x * per, nend = min(s + per, N);
    for (int n0 = s; n0 < nend; n0 += 4) {
        int n = n0 + sub;
        bool act = n < nend;
        if (act) {
            const float* xr = x + (size_t)n * FDIM;
            const float* vr = vmsg + (size_t)n * HID;
            for (int k = j64; k < 261; k += 64) z[sub][k] = (k < FDIM) ? xr[k] : vr[k - FDIM];
        }
        __syncthreads();
        if (act) {
            float acc = bj;
#pragma unroll
            for (int kq = 0; kq < 66; ++kq) {
                uint2 u = w[kq * 64 + j64];
                float4 zv = *reinterpret_cast<const float4*>(&z[sub][4 * kq]);
                acc += lo16(u.x) * zv.x + hi16(u.x) * zv.y + lo16(u.y) * zv.z + hi16(u.y) * zv.w;
            }
            int gg = batch[n];
            atomicAdd(&sums[(size_t)gg * HID + j], fmaxf(acc, 0.f));
            if (half == 0 && j64 == 0) atomicAdd(&counts[gg], 1.0f);
        }
        __syncthreads();
    }
}

__global__ void k_out(const float* __restrict__ sums, const float* __restrict__ counts,
                      const float* __restrict__ Wfc, const float* __restrict__ bfc,
                      float* __restrict__ out, int G) {
    __shared__ float pooled[HID];
    const int g = blockIdx.x, tid = threadIdx.x;  // 64 threads
    float inv = 1.0f / fmaxf(counts[g], 1.0f);
    pooled[tid] = sums[(size_t)g * HID + tid] * inv;
    pooled[tid + 64] = sums[(size_t)g * HID + tid + 64] * inv;
    __syncthreads();
    float acc = bfc[tid];
#pragma unroll
    for (int k = 0; k < HID; ++k) acc += Wfc[tid * HID + k] * pooled[k];
    out[(size_t)g * 64 + tid] = tanhf(acc);
}

extern "C" void kernel_launch(void* const* d_in, const int* in_sizes, int n_in,
                              void* d_out, int out_size, void* d_ws, size_t ws_size,
                              hipStream_t stream) {
    const float* x     = (const float*)d_in[0];
    const int*   ei    = (const int*)d_in[1];
    const float* eattr = (const float*)d_in[3];
    const int*   batch = (const int*)d_in[4];
    const float* W1    = (const float*)d_in[6];
    const float* W2    = (const float*)d_in[7];
    const float* W3    = (const float*)d_in[8];
    const float* b3    = (const float*)d_in[9];
    const float* Wfc   = (const float*)d_in[10];
    const float* bfc   = (const float*)d_in[11];
    float* out = (float*)d_out;
    (void)n_in;

    const int N = in_sizes[0] / FDIM;
    const int E = in_sizes[3];
    const int G = out_size / 64;
    const int* src = ei;
    const int* dst = ei + E;

    char* ws = (char*)d_ws;
    size_t o = 0;
    bf16* h      = (bf16*)(ws + o); o += (size_t)E * HID * sizeof(bf16);
    float* mnode = (float*)(ws + o); o += (size_t)N * HID * sizeof(float);
    // the following block [sums..cursor] is zeroed in one pass
    size_t o_zero = o;
    float* sums  = (float*)(ws + o); o += (size_t)G * HID * sizeof(float);
    float* counts= (float*)(ws + o); o += (size_t)G * sizeof(float);
    int* deg     = (int*)(ws + o);   o += (size_t)N * sizeof(int);
    int* cursor  = (int*)(ws + o);   o += (size_t)N * sizeof(int);
    size_t zero_n = (o - o_zero) / 4;
    int* offs    = (int*)(ws + o);   o += (size_t)N * sizeof(int);
    int* csr     = (int*)(ws + o);   o += (size_t)E * sizeof(int);
    int* bsum    = (int*)(ws + o);   o += 256 * sizeof(int);
    size_t o_h0  = (o + 255) & ~(size_t)255;
    bool useH0 = ws_size >= o_h0 + (size_t)E * HID * sizeof(bf16);
    bf16* h0     = (bf16*)(ws + o_h0);

    const int SM_A = 32768 + 1088;
    const int SM_B = 32768 + 1088 + 34816 + 1088;
    if (!useH0) {
        hipFuncSetAttribute(reinterpret_cast<const void*>(k_update<false>),
                            hipFuncAttributeMaxDynamicSharedMemorySize, SM_B);
    }

    const int eGrid = (E + 255) / 256;
    const int nGrid = (N + 255) / 256;
    const int nbScan = (N + 1023) / 1024;

    // zero sums|counts|deg|cursor (contiguous)
    k_zero<<<512, 256, 0, stream>>>((float*)(ws + o_zero), (long long)zero_n);

    // h (and h0 copy)
    k_h0<<<2048, 256, 0, stream>>>(x, src, eattr, W1, h, useH0 ? h0 : (bf16*)nullptr, E);

    // CSR build (overlaps k_h0's tail only via stream order; cheap anyway)
    k_hist<<<eGrid, 256, 0, stream>>>(dst, deg, E);
    k_scanA<<<nbScan, 256, 0, stream>>>(deg, offs, bsum, N);
    k_scanB<<<1, 256, 0, stream>>>(bsum, nbScan);
    k_scanC<<<nGrid, 256, 0, stream>>>(offs, bsum, N);
    k_fill<<<eGrid, 256, 0, stream>>>(dst, offs, cursor, csr, E);

    // iter 1
    k_gather<<<2048, 256, 0, stream>>>(h, csr, offs, deg, mnode, N);
    if (useH0) k_update<true><<<2048, 256, SM_A, stream>>>(src, x, eattr, mnode, h0, h, W1, W2, E);
    else       k_update<false><<<2048, 256, SM_B, stream>>>(src, x, eattr, mnode, nullptr, h, W1, W2, E);

    // iter 2
    k_gather<<<2048, 256, 0, stream>>>(h, csr, offs, deg, mnode, N);
    if (useH0) k_update<true><<<2048, 256, SM_A, stream>>>(src, x, eattr, mnode, h0, h, W1, W2, E);
    else       k_update<false><<<2048, 256, SM_B, stream>>>(src, x, eattr, mnode, nullptr, h, W1, W2, E);

    // final v_msg
    k_gather<<<2048, 256, 0, stream>>>(h, csr, offs, deg, mnode, N);

    k_node<<<dim3(1024, 2), 256, 0, stream>>>(x, mnode, W3, b3, batch, sums, counts, N);
    k_out<<<G, 64, 0, stream>>>(sums, counts, Wfc, bfc, out, G);
}

// Round 4
// 846.598 us; speedup vs baseline: 4.4227x; 2.2262x over previous
//
#include <hip/hip_runtime.h>
#include <hip/hip_bf16.h>

#define HID 128
#define FDIM 133

typedef __hip_bfloat16 bf16;
typedef unsigned short u16;
typedef __attribute__((ext_vector_type(8))) short short8;
typedef __attribute__((ext_vector_type(4))) float v4f;

__device__ __forceinline__ float b2f(bf16 v) { return __bfloat162float(v); }
__device__ __forceinline__ u16 bbits(float v) {
    union { bf16 b; u16 u; } cv; cv.b = __float2bfloat16(v); return cv.u;
}
__device__ __forceinline__ float lo16(unsigned u) { return __uint_as_float(u << 16); }
__device__ __forceinline__ float hi16(unsigned u) { return __uint_as_float(u & 0xffff0000u); }
__device__ __forceinline__ float u2f(u16 u) { return __uint_as_float((unsigned)u << 16); }
__device__ __forceinline__ unsigned pksub(unsigned a, unsigned b) {
    float lo = lo16(a) - lo16(b);
    float hi = hi16(a) - hi16(b);
    return (unsigned)bbits(lo) | ((unsigned)bbits(hi) << 16);
}

__global__ void k_zero(float* __restrict__ p, long long n) {
    long long i = (long long)blockIdx.x * blockDim.x + threadIdx.x;
    long long st = (long long)gridDim.x * blockDim.x;
    for (; i < n; i += st) p[i] = 0.f;
}

// xb[n][136] = bf16(x[n][0..132]), 0 pad for 133..135
__global__ void k_cast(const float* __restrict__ x, u16* __restrict__ xb, int N) {
    int i = blockIdx.x * blockDim.x + threadIdx.x;
    int st = gridDim.x * blockDim.x;
    int total = N * 136;
    for (; i < total; i += st) {
        int n = i / 136, k = i - n * 136;
        float v = (k < FDIM) ? x[(size_t)n * FDIM + k] : 0.f;
        xb[i] = bbits(v);
    }
}

// ---------------- CSR build (incoming edges per dst) ----------------
__global__ void k_hist(const int* __restrict__ dst, int* __restrict__ deg, int E) {
    int i = blockIdx.x * blockDim.x + threadIdx.x;
    if (i < E) atomicAdd(&deg[dst[i]], 1);
}

__global__ void k_scanA(const int* __restrict__ deg, int* __restrict__ offs,
                        int* __restrict__ bsum, int N) {
    __shared__ int sh[256];
    int t = threadIdx.x;
    int base = blockIdx.x * 1024 + t * 4;
    int d0 = (base + 0 < N) ? deg[base + 0] : 0;
    int d1 = (base + 1 < N) ? deg[base + 1] : 0;
    int d2 = (base + 2 < N) ? deg[base + 2] : 0;
    int d3 = (base + 3 < N) ? deg[base + 3] : 0;
    sh[t] = d0 + d1 + d2 + d3;
    __syncthreads();
    for (int off = 1; off < 256; off <<= 1) {
        int v = (t >= off) ? sh[t - off] : 0;
        __syncthreads();
        sh[t] += v;
        __syncthreads();
    }
    int o = (t > 0) ? sh[t - 1] : 0;
    if (t == 255) bsum[blockIdx.x] = sh[255];
    if (base + 0 < N) offs[base + 0] = o; o += d0;
    if (base + 1 < N) offs[base + 1] = o; o += d1;
    if (base + 2 < N) offs[base + 2] = o; o += d2;
    if (base + 3 < N) offs[base + 3] = o;
}

__global__ void k_scanB(int* __restrict__ bsum, int nb) {
    __shared__ int sh[256];
    int t = threadIdx.x;
    sh[t] = (t < nb) ? bsum[t] : 0;
    __syncthreads();
    for (int off = 1; off < 256; off <<= 1) {
        int v = (t >= off) ? sh[t - off] : 0;
        __syncthreads();
        sh[t] += v;
        __syncthreads();
    }
    if (t < nb) bsum[t] = (t > 0) ? sh[t - 1] : 0;
}

__global__ void k_scanC(int* __restrict__ offs, const int* __restrict__ bsum, int N) {
    int i = blockIdx.x * blockDim.x + threadIdx.x;
    if (i < N) offs[i] += bsum[i >> 10];
}

__global__ void k_fill(const int* __restrict__ dst, const int* __restrict__ offs,
                       int* __restrict__ cursor, int* __restrict__ csr, int E) {
    int e = blockIdx.x * blockDim.x + threadIdx.x;
    if (e < E) {
        int d = dst[e];
        int p = offs[d] + atomicAdd(&cursor[d], 1);
        csr[p] = e;
    }
}

// mnb[n] (bf16) = sum of h rows over incoming edges (one wave per node)
__global__ void k_gather(const u16* __restrict__ h, const int* __restrict__ csr,
                         const int* __restrict__ offs, const int* __restrict__ deg,
                         u16* __restrict__ mnb, int N) {
    int gw = (blockIdx.x * blockDim.x + threadIdx.x) >> 6;
    int lane = threadIdx.x & 63;
    int nw = (gridDim.x * blockDim.x) >> 6;
    for (int n = gw; n < N; n += nw) {
        int s = offs[n], d = deg[n];
        float a0 = 0.f, a1 = 0.f;
        for (int i = 0; i < d; ++i) {
            int e = csr[s + i];
            unsigned u = *reinterpret_cast<const unsigned*>(h + (size_t)e * HID + 2 * lane);
            a0 += lo16(u);
            a1 += hi16(u);
        }
        *reinterpret_cast<unsigned*>(mnb + (size_t)n * HID + 2 * lane) =
            (unsigned)bbits(a0) | ((unsigned)bbits(a1) << 16);
    }
}

// ---------------- MFMA edge kernels ----------------
// h0/h[e][j] = relu(sum_k W1[j][k] * [xb[src[e]], eattr]), 64-edge tiles, K=160
__global__ void k_h0m(const u16* __restrict__ xb, const int* __restrict__ src,
                      const float* __restrict__ eattr, const float* __restrict__ W1,
                      u16* __restrict__ h, u16* __restrict__ h0, int E) {
    __shared__ __align__(16) char lds[61440];
    char* bfr = lds;               // 40 frags (s*8+t) x 1024 B
    char* afr = lds + 40960;       // 20 frags (m*5+s) x 1024 B
    const int tid = threadIdx.x, l = tid & 63, w = tid >> 6;

    for (int idx = tid; idx < 40 * 64; idx += 256) {
        int f = idx >> 6, ln = idx & 63;
        int s = f >> 3, t = f & 7;
        int n = t * 16 + (ln & 15);
        int k0 = s * 32 + (ln >> 4) * 8;
        u16 u[8];
#pragma unroll
        for (int i = 0; i < 8; ++i) {
            int k = k0 + i;
            u[i] = (k < FDIM + 1) ? bbits(W1[n * (FDIM + 1) + k]) : (u16)0;
        }
        uint4 v;
        v.x = u[0] | ((unsigned)u[1] << 16);
        v.y = u[2] | ((unsigned)u[3] << 16);
        v.z = u[4] | ((unsigned)u[5] << 16);
        v.w = u[6] | ((unsigned)u[7] << 16);
        *reinterpret_cast<uint4*>(bfr + idx * 16) = v;
    }
    __syncthreads();

    const int ntiles = (E + 63) >> 6;
    for (int tile = blockIdx.x; tile < ntiles; tile += gridDim.x) {
        int e0 = tile << 6;
        for (int idx = tid; idx < 1280; idx += 256) {
            int m = idx / 320;
            int rem = idx - m * 320;
            int s = rem >> 6, ln = rem & 63;
            int row = m * 16 + (ln & 15);
            int e = e0 + row;
            int k0 = s * 32 + (ln >> 4) * 8;
            uint4 v = make_uint4(0, 0, 0, 0);
            if (e < E && k0 < 136) {
                int sn = src[e];
                v = *reinterpret_cast<const uint4*>(xb + (size_t)sn * 136 + k0);
                if (k0 == 128)  // inject eattr at k=133 (elem 5 -> hi half of .z)
                    v.z = (v.z & 0xFFFFu) | ((unsigned)bbits(eattr[e]) << 16);
            }
            *reinterpret_cast<uint4*>(afr + ((m * 5 + s) * 64 + ln) * 16) = v;
        }
        __syncthreads();

        v4f acc[8];
#pragma unroll
        for (int t = 0; t < 8; ++t) acc[t] = (v4f){0.f, 0.f, 0.f, 0.f};
#pragma unroll
        for (int s = 0; s < 5; ++s) {
            short8 af = *reinterpret_cast<short8*>(afr + ((w * 5 + s) * 64 + l) * 16);
#pragma unroll
            for (int t = 0; t < 8; ++t) {
                short8 bv = *reinterpret_cast<short8*>(bfr + ((s * 8 + t) * 64 + l) * 16);
                acc[t] = __builtin_amdgcn_mfma_f32_16x16x32_bf16(af, bv, acc[t], 0, 0, 0);
            }
        }
        // bounce D through wave-private LDS (reuses this wave's afrag region)
        char* wb = afr + w * 5120;
#pragma unroll
        for (int t = 0; t < 8; ++t)
#pragma unroll
            for (int r = 0; r < 4; ++r) {
                int row = (l >> 4) * 4 + r;
                int cb = (t * 16 + (l & 15)) * 2;
                *reinterpret_cast<u16*>(wb + row * 256 + (cb ^ ((row & 7) << 4))) =
                    bbits(fmaxf(acc[t][r], 0.f));
            }
#pragma unroll
        for (int p = 0; p < 4; ++p) {
            int row = l >> 2, q = l & 3;
            int off = q * 16 + p * 64;
            uint4 v = *reinterpret_cast<uint4*>(wb + row * 256 + (off ^ ((row & 7) << 4)));
            int e = e0 + w * 16 + row;
            if (e < E) {
                *reinterpret_cast<uint4*>((char*)(h + (size_t)e * HID) + off) = v;
                *reinterpret_cast<uint4*>((char*)(h0 + (size_t)e * HID) + off) = v;
            }
        }
        __syncthreads();
    }
}

// h[e] = relu(h0[e] + W2*(mnb[src[e]] - h[e^1])), in place per 64-edge tile, K=128
__global__ void k_updm(const int* __restrict__ src, const u16* __restrict__ mnb,
                       const u16* __restrict__ h0, u16* __restrict__ h,
                       const float* __restrict__ W2, int E) {
    __shared__ __align__(16) char lds[49152];
    char* bfr = lds;               // 32 frags (s*8+t) x 1024 B
    char* afr = lds + 32768;       // 16 frags (m*4+s) x 1024 B
    const int tid = threadIdx.x, l = tid & 63, w = tid >> 6;

    for (int idx = tid; idx < 32 * 64; idx += 256) {
        int f = idx >> 6, ln = idx & 63;
        int s = f >> 3, t = f & 7;
        int n = t * 16 + (ln & 15);
        int k0 = s * 32 + (ln >> 4) * 8;
        const float* wr = W2 + (size_t)n * HID + k0;
        uint4 v;
        v.x = bbits(wr[0]) | ((unsigned)bbits(wr[1]) << 16);
        v.y = bbits(wr[2]) | ((unsigned)bbits(wr[3]) << 16);
        v.z = bbits(wr[4]) | ((unsigned)bbits(wr[5]) << 16);
        v.w = bbits(wr[6]) | ((unsigned)bbits(wr[7]) << 16);
        *reinterpret_cast<uint4*>(bfr + idx * 16) = v;
    }
    __syncthreads();

    const int ntiles = (E + 63) >> 6;
    for (int tile = blockIdx.x; tile < ntiles; tile += gridDim.x) {
        int e0 = tile << 6;
        for (int idx = tid; idx < 1024; idx += 256) {
            int m = idx >> 8;
            int s = (idx >> 6) & 3, ln = idx & 63;
            int row = m * 16 + (ln & 15);
            int e = e0 + row;
            int k0 = s * 32 + (ln >> 4) * 8;
            uint4 v = make_uint4(0, 0, 0, 0);
            if (e < E) {
                int sn = src[e];
                uint4 a = *reinterpret_cast<const uint4*>(mnb + (size_t)sn * HID + k0);
                uint4 b = *reinterpret_cast<const uint4*>(h + (size_t)(e ^ 1) * HID + k0);
                v.x = pksub(a.x, b.x);
                v.y = pksub(a.y, b.y);
                v.z = pksub(a.z, b.z);
                v.w = pksub(a.w, b.w);
            }
            *reinterpret_cast<uint4*>(afr + ((m * 4 + s) * 64 + ln) * 16) = v;
        }
        // h0 preload in D layout (independent of LDS; overlaps with MFMA)
        u16 h0r[8][4];
        {
            int rbase = e0 + w * 16 + (l >> 4) * 4;
            int cbase = l & 15;
#pragma unroll
            for (int t = 0; t < 8; ++t)
#pragma unroll
                for (int r = 0; r < 4; ++r)
                    h0r[t][r] = h0[(size_t)(rbase + r) * HID + t * 16 + cbase];
        }
        __syncthreads();

        v4f acc[8];
#pragma unroll
        for (int t = 0; t < 8; ++t) acc[t] = (v4f){0.f, 0.f, 0.f, 0.f};
#pragma unroll
        for (int s = 0; s < 4; ++s) {
            short8 af = *reinterpret_cast<short8*>(afr + ((w * 4 + s) * 64 + l) * 16);
#pragma unroll
            for (int t = 0; t < 8; ++t) {
                short8 bv = *reinterpret_cast<short8*>(bfr + ((s * 8 + t) * 64 + l) * 16);
                acc[t] = __builtin_amdgcn_mfma_f32_16x16x32_bf16(af, bv, acc[t], 0, 0, 0);
            }
        }
        char* wb = afr + w * 4096;
#pragma unroll
        for (int t = 0; t < 8; ++t)
#pragma unroll
            for (int r = 0; r < 4; ++r) {
                int row = (l >> 4) * 4 + r;
                int cb = (t * 16 + (l & 15)) * 2;
                *reinterpret_cast<u16*>(wb + row * 256 + (cb ^ ((row & 7) << 4))) =
                    bbits(fmaxf(acc[t][r] + u2f(h0r[t][r]), 0.f));
            }
#pragma unroll
        for (int p = 0; p < 4; ++p) {
            int row = l >> 2, q = l & 3;
            int off = q * 16 + p * 64;
            uint4 v = *reinterpret_cast<uint4*>(wb + row * 256 + (off ^ ((row & 7) << 4)));
            int e = e0 + w * 16 + row;
            if (e < E)
                *reinterpret_cast<uint4*>((char*)(h + (size_t)e * HID) + off) = v;
        }
        __syncthreads();
    }
}

// ---------------- node MLP + fused mean-pool (scalar, unchanged) ----------------
__global__ void k_node(const float* __restrict__ x, const u16* __restrict__ vmsg,
                       const float* __restrict__ W3, const float* __restrict__ b3,
                       const int* __restrict__ batch, float* __restrict__ sums,
                       float* __restrict__ counts, int N) {
    __shared__ uint2 w[66 * 64];
    __shared__ __align__(16) float z[4][264];
    const int tid = threadIdx.x, sub = tid >> 6, j64 = tid & 63;
    const int half = blockIdx.y;
    for (int idx = tid; idx < 66 * 64; idx += 256) {
        int kq = idx >> 6, jj = idx & 63, k = 4 * kq;
        const float* wr = W3 + (size_t)(half * 64 + jj) * 261;
        float v0 = (k + 0 < 261) ? wr[k + 0] : 0.f;
        float v1 = (k + 1 < 261) ? wr[k + 1] : 0.f;
        float v2 = (k + 2 < 261) ? wr[k + 2] : 0.f;
        float v3 = (k + 3 < 261) ? wr[k + 3] : 0.f;
        w[idx] = make_uint2((unsigned)bbits(v0) | ((unsigned)bbits(v1) << 16),
                            (unsigned)bbits(v2) | ((unsigned)bbits(v3) << 16));
    }
    if (tid < 12) { int r = tid / 3, c = tid % 3; z[r][261 + c] = 0.f; }
    __syncthreads();
    const int j = half * 64 + j64;
    const float bj = b3[j];
    int g = gridDim.x;
    int per = ((N + 4 * g - 1) / (4 * g)) * 4;
    int s = blockIdx.x * per, nend = min(s + per, N);
    for (int n0 = s; n0 < nend; n0 += 4) {
        int n = n0 + sub;
        bool act = n < nend;
        if (act) {
            const float* xr = x + (size_t)n * FDIM;
            const u16* vr = vmsg + (size_t)n * HID;
            for (int k = j64; k < 261; k += 64)
                z[sub][k] = (k < FDIM) ? xr[k] : u2f(vr[k - FDIM]);
        }
        __syncthreads();
        if (act) {
            float acc = bj;
#pragma unroll
            for (int kq = 0; kq < 66; ++kq) {
                uint2 u = w[kq * 64 + j64];
                float4 zv = *reinterpret_cast<const float4*>(&z[sub][4 * kq]);
                acc += lo16(u.x) * zv.x + hi16(u.x) * zv.y + lo16(u.y) * zv.z + hi16(u.y) * zv.w;
            }
            int gg = batch[n];
            atomicAdd(&sums[(size_t)gg * HID + j], fmaxf(acc, 0.f));
            if (half == 0 && j64 == 0) atomicAdd(&counts[gg], 1.0f);
        }
        __syncthreads();
    }
}

__global__ void k_out(const float* __restrict__ sums, const float* __restrict__ counts,
                      const float* __restrict__ Wfc, const float* __restrict__ bfc,
                      float* __restrict__ out, int G) {
    __shared__ float pooled[HID];
    const int g = blockIdx.x, tid = threadIdx.x;  // 64 threads
    float inv = 1.0f / fmaxf(counts[g], 1.0f);
    pooled[tid] = sums[(size_t)g * HID + tid] * inv;
    pooled[tid + 64] = sums[(size_t)g * HID + tid + 64] * inv;
    __syncthreads();
    float acc = bfc[tid];
#pragma unroll
    for (int k = 0; k < HID; ++k) acc += Wfc[tid * HID + k] * pooled[k];
    out[(size_t)g * 64 + tid] = tanhf(acc);
}

extern "C" void kernel_launch(void* const* d_in, const int* in_sizes, int n_in,
                              void* d_out, int out_size, void* d_ws, size_t ws_size,
                              hipStream_t stream) {
    const float* x     = (const float*)d_in[0];
    const int*   ei    = (const int*)d_in[1];
    const float* eattr = (const float*)d_in[3];
    const int*   batch = (const int*)d_in[4];
    const float* W1    = (const float*)d_in[6];
    const float* W2    = (const float*)d_in[7];
    const float* W3    = (const float*)d_in[8];
    const float* b3    = (const float*)d_in[9];
    const float* Wfc   = (const float*)d_in[10];
    const float* bfc   = (const float*)d_in[11];
    float* out = (float*)d_out;
    (void)n_in; (void)ws_size;

    const int N = in_sizes[0] / FDIM;
    const int E = in_sizes[3];
    const int G = out_size / 64;
    const int* src = ei;
    const int* dst = ei + E;

    char* ws = (char*)d_ws;
    size_t o = 0;
    u16* h   = (u16*)(ws + o); o += (size_t)E * HID * 2;
    u16* h0  = (u16*)(ws + o); o += (size_t)E * HID * 2;
    u16* xb  = (u16*)(ws + o); o += (size_t)N * 136 * 2;
    u16* mnb = (u16*)(ws + o); o += (size_t)N * HID * 2;
    size_t o_zero = o;
    float* sums   = (float*)(ws + o); o += (size_t)G * HID * 4;
    float* counts = (float*)(ws + o); o += (size_t)G * 4;
    int* deg    = (int*)(ws + o); o += (size_t)N * 4;
    int* cursor = (int*)(ws + o); o += (size_t)N * 4;
    size_t zero_n = (o - o_zero) / 4;
    int* offs   = (int*)(ws + o); o += (size_t)N * 4;
    int* csr    = (int*)(ws + o); o += (size_t)E * 4;
    int* bsum   = (int*)(ws + o); o += 256 * 4;

    const int eGrid = (E + 255) / 256;
    const int nGrid = (N + 255) / 256;
    const int nbScan = (N + 1023) / 1024;

    k_zero<<<512, 256, 0, stream>>>((float*)(ws + o_zero), (long long)zero_n);
    k_cast<<<2048, 256, 0, stream>>>(x, xb, N);

    k_hist<<<eGrid, 256, 0, stream>>>(dst, deg, E);
    k_scanA<<<nbScan, 256, 0, stream>>>(deg, offs, bsum, N);
    k_scanB<<<1, 256, 0, stream>>>(bsum, nbScan);
    k_scanC<<<nGrid, 256, 0, stream>>>(offs, bsum, N);
    k_fill<<<eGrid, 256, 0, stream>>>(dst, offs, cursor, csr, E);

    k_h0m<<<2048, 256, 0, stream>>>(xb, src, eattr, W1, h, h0, E);

    k_gather<<<2048, 256, 0, stream>>>(h, csr, offs, deg, mnb, N);
    k_updm<<<2048, 256, 0, stream>>>(src, mnb, h0, h, W2, E);

    k_gather<<<2048, 256, 0, stream>>>(h, csr, offs, deg, mnb, N);
    k_updm<<<2048, 256, 0, stream>>>(src, mnb, h0, h, W2, E);

    k_gather<<<2048, 256, 0, stream>>>(h, csr, offs, deg, mnb, N);

    k_node<<<dim3(1024, 2), 256, 0, stream>>>(x, mnb, W3, b3, batch, sums, counts, N);
    k_out<<<G, 64, 0, stream>>>(sums, counts, Wfc, bfc, out, G);
}

// Round 5
// 688.678 us; speedup vs baseline: 5.4368x; 1.2293x over previous
//
#include <hip/hip_runtime.h>
#include <hip/hip_bf16.h>

#define HID 128
#define FDIM 133

typedef __hip_bfloat16 bf16;
typedef unsigned short u16;
typedef __attribute__((ext_vector_type(8))) short short8;
typedef __attribute__((ext_vector_type(4))) float v4f;

__device__ __forceinline__ float b2f(bf16 v) { return __bfloat162float(v); }
__device__ __forceinline__ u16 bbits(float v) {
    union { bf16 b; u16 u; } cv; cv.b = __float2bfloat16(v); return cv.u;
}
__device__ __forceinline__ float lo16(unsigned u) { return __uint_as_float(u << 16); }
__device__ __forceinline__ float hi16(unsigned u) { return __uint_as_float(u & 0xffff0000u); }
__device__ __forceinline__ float u2f(u16 u) { return __uint_as_float((unsigned)u << 16); }
__device__ __forceinline__ unsigned pksub(unsigned a, unsigned b) {
    float lo = lo16(a) - lo16(b);
    float hi = hi16(a) - hi16(b);
    return (unsigned)bbits(lo) | ((unsigned)bbits(hi) << 16);
}

__global__ void k_zero(float* __restrict__ p, long long n) {
    long long i = (long long)blockIdx.x * blockDim.x + threadIdx.x;
    long long st = (long long)gridDim.x * blockDim.x;
    for (; i < n; i += st) p[i] = 0.f;
}

// xb[n][136] = bf16(x[n][0..132]), 0 pad for 133..135
__global__ void k_cast(const float* __restrict__ x, u16* __restrict__ xb, int N) {
    int i = blockIdx.x * blockDim.x + threadIdx.x;
    int st = gridDim.x * blockDim.x;
    int total = N * 136;
    for (; i < total; i += st) {
        int n = i / 136, k = i - n * 136;
        float v = (k < FDIM) ? x[(size_t)n * FDIM + k] : 0.f;
        xb[i] = bbits(v);
    }
}

// ---------------- CSR build (incoming edges per dst) ----------------
__global__ void k_hist(const int* __restrict__ dst, int* __restrict__ deg, int E) {
    int i = blockIdx.x * blockDim.x + threadIdx.x;
    if (i < E) atomicAdd(&deg[dst[i]], 1);
}

__global__ void k_scanA(const int* __restrict__ deg, int* __restrict__ offs,
                        int* __restrict__ bsum, int N) {
    __shared__ int sh[256];
    int t = threadIdx.x;
    int base = blockIdx.x * 1024 + t * 4;
    int d0 = (base + 0 < N) ? deg[base + 0] : 0;
    int d1 = (base + 1 < N) ? deg[base + 1] : 0;
    int d2 = (base + 2 < N) ? deg[base + 2] : 0;
    int d3 = (base + 3 < N) ? deg[base + 3] : 0;
    sh[t] = d0 + d1 + d2 + d3;
    __syncthreads();
    for (int off = 1; off < 256; off <<= 1) {
        int v = (t >= off) ? sh[t - off] : 0;
        __syncthreads();
        sh[t] += v;
        __syncthreads();
    }
    int o = (t > 0) ? sh[t - 1] : 0;
    if (t == 255) bsum[blockIdx.x] = sh[255];
    if (base + 0 < N) offs[base + 0] = o; o += d0;
    if (base + 1 < N) offs[base + 1] = o; o += d1;
    if (base + 2 < N) offs[base + 2] = o; o += d2;
    if (base + 3 < N) offs[base + 3] = o;
}

__global__ void k_scanB(int* __restrict__ bsum, int nb) {
    __shared__ int sh[256];
    int t = threadIdx.x;
    sh[t] = (t < nb) ? bsum[t] : 0;
    __syncthreads();
    for (int off = 1; off < 256; off <<= 1) {
        int v = (t >= off) ? sh[t - off] : 0;
        __syncthreads();
        sh[t] += v;
        __syncthreads();
    }
    if (t < nb) bsum[t] = (t > 0) ? sh[t - 1] : 0;
}

__global__ void k_scanC(int* __restrict__ offs, const int* __restrict__ bsum, int N) {
    int i = blockIdx.x * blockDim.x + threadIdx.x;
    if (i < N) offs[i] += bsum[i >> 10];
}

__global__ void k_fill(const int* __restrict__ dst, const int* __restrict__ offs,
                       int* __restrict__ cursor, int* __restrict__ csr, int E) {
    int e = blockIdx.x * blockDim.x + threadIdx.x;
    if (e < E) {
        int d = dst[e];
        int p = offs[d] + atomicAdd(&cursor[d], 1);
        csr[p] = e;
    }
}

// counts[g] = #nodes with batch==g (batch sorted -> binary search, no atomics)
__global__ void k_counts(const int* __restrict__ batch, float* __restrict__ counts,
                         int N, int G) {
    int g = blockIdx.x * blockDim.x + threadIdx.x;
    if (g >= G) return;
    int lo = 0, hi = N;
    while (lo < hi) { int mid = (lo + hi) >> 1; if (batch[mid] < g) lo = mid + 1; else hi = mid; }
    int lb0 = lo;
    lo = 0; hi = N;
    while (lo < hi) { int mid = (lo + hi) >> 1; if (batch[mid] < g + 1) lo = mid + 1; else hi = mid; }
    counts[g] = (float)(lo - lb0);
}

// mnb[n] (bf16) = sum of h rows over incoming edges (one wave per node)
__global__ void k_gather(const u16* __restrict__ h, const int* __restrict__ csr,
                         const int* __restrict__ offs, const int* __restrict__ deg,
                         u16* __restrict__ mnb, int N) {
    int gw = (blockIdx.x * blockDim.x + threadIdx.x) >> 6;
    int lane = threadIdx.x & 63;
    int nw = (gridDim.x * blockDim.x) >> 6;
    for (int n = gw; n < N; n += nw) {
        int s = offs[n], d = deg[n];
        float a0 = 0.f, a1 = 0.f;
        for (int i = 0; i < d; ++i) {
            int e = csr[s + i];
            unsigned u = *reinterpret_cast<const unsigned*>(h + (size_t)e * HID + 2 * lane);
            a0 += lo16(u);
            a1 += hi16(u);
        }
        *reinterpret_cast<unsigned*>(mnb + (size_t)n * HID + 2 * lane) =
            (unsigned)bbits(a0) | ((unsigned)bbits(a1) << 16);
    }
}

// ---------------- MFMA edge kernels ----------------
// h0/h[e][j] = relu(sum_k W1[j][k] * [xb[src[e]], eattr]), 64-edge tiles, K=160
__global__ void k_h0m(const u16* __restrict__ xb, const int* __restrict__ src,
                      const float* __restrict__ eattr, const float* __restrict__ W1,
                      u16* __restrict__ h, u16* __restrict__ h0, int E) {
    __shared__ __align__(16) char lds[61440];
    char* bfr = lds;               // 40 frags (s*8+t) x 1024 B
    char* afr = lds + 40960;       // 20 frags (m*5+s) x 1024 B
    const int tid = threadIdx.x, l = tid & 63, w = tid >> 6;

    for (int idx = tid; idx < 40 * 64; idx += 256) {
        int f = idx >> 6, ln = idx & 63;
        int s = f >> 3, t = f & 7;
        int n = t * 16 + (ln & 15);
        int k0 = s * 32 + (ln >> 4) * 8;
        u16 u[8];
#pragma unroll
        for (int i = 0; i < 8; ++i) {
            int k = k0 + i;
            u[i] = (k < FDIM + 1) ? bbits(W1[n * (FDIM + 1) + k]) : (u16)0;
        }
        uint4 v;
        v.x = u[0] | ((unsigned)u[1] << 16);
        v.y = u[2] | ((unsigned)u[3] << 16);
        v.z = u[4] | ((unsigned)u[5] << 16);
        v.w = u[6] | ((unsigned)u[7] << 16);
        *reinterpret_cast<uint4*>(bfr + idx * 16) = v;
    }
    __syncthreads();

    const int ntiles = (E + 63) >> 6;
    for (int tile = blockIdx.x; tile < ntiles; tile += gridDim.x) {
        int e0 = tile << 6;
        for (int idx = tid; idx < 1280; idx += 256) {
            int m = idx / 320;
            int rem = idx - m * 320;
            int s = rem >> 6, ln = rem & 63;
            int row = m * 16 + (ln & 15);
            int e = e0 + row;
            int k0 = s * 32 + (ln >> 4) * 8;
            uint4 v = make_uint4(0, 0, 0, 0);
            if (e < E && k0 < 136) {
                int sn = src[e];
                v = *reinterpret_cast<const uint4*>(xb + (size_t)sn * 136 + k0);
                if (k0 == 128)  // inject eattr at k=133 (elem 5 -> hi half of .z)
                    v.z = (v.z & 0xFFFFu) | ((unsigned)bbits(eattr[e]) << 16);
            }
            *reinterpret_cast<uint4*>(afr + ((m * 5 + s) * 64 + ln) * 16) = v;
        }
        __syncthreads();

        v4f acc[8];
#pragma unroll
        for (int t = 0; t < 8; ++t) acc[t] = (v4f){0.f, 0.f, 0.f, 0.f};
#pragma unroll
        for (int s = 0; s < 5; ++s) {
            short8 af = *reinterpret_cast<short8*>(afr + ((w * 5 + s) * 64 + l) * 16);
#pragma unroll
            for (int t = 0; t < 8; ++t) {
                short8 bv = *reinterpret_cast<short8*>(bfr + ((s * 8 + t) * 64 + l) * 16);
                acc[t] = __builtin_amdgcn_mfma_f32_16x16x32_bf16(af, bv, acc[t], 0, 0, 0);
            }
        }
        // bounce D through wave-private LDS (reuses this wave's afrag region)
        char* wb = afr + w * 5120;
#pragma unroll
        for (int t = 0; t < 8; ++t)
#pragma unroll
            for (int r = 0; r < 4; ++r) {
                int row = (l >> 4) * 4 + r;
                int cb = (t * 16 + (l & 15)) * 2;
                *reinterpret_cast<u16*>(wb + row * 256 + (cb ^ ((row & 7) << 4))) =
                    bbits(fmaxf(acc[t][r], 0.f));
            }
#pragma unroll
        for (int p = 0; p < 4; ++p) {
            int row = l >> 2, q = l & 3;
            int off = q * 16 + p * 64;
            uint4 v = *reinterpret_cast<uint4*>(wb + row * 256 + (off ^ ((row & 7) << 4)));
            int e = e0 + w * 16 + row;
            if (e < E) {
                *reinterpret_cast<uint4*>((char*)(h + (size_t)e * HID) + off) = v;
                *reinterpret_cast<uint4*>((char*)(h0 + (size_t)e * HID) + off) = v;
            }
        }
        __syncthreads();
    }
}

// h[e] = relu(h0[e] + W2*(mnb[src[e]] - h[e^1])), in place per 64-edge tile, K=128
__global__ void k_updm(const int* __restrict__ src, const u16* __restrict__ mnb,
                       const u16* __restrict__ h0, u16* __restrict__ h,
                       const float* __restrict__ W2, int E) {
    __shared__ __align__(16) char lds[49152];
    char* bfr = lds;               // 32 frags (s*8+t) x 1024 B
    char* afr = lds + 32768;       // 16 frags (m*4+s) x 1024 B
    const int tid = threadIdx.x, l = tid & 63, w = tid >> 6;

    for (int idx = tid; idx < 32 * 64; idx += 256) {
        int f = idx >> 6, ln = idx & 63;
        int s = f >> 3, t = f & 7;
        int n = t * 16 + (ln & 15);
        int k0 = s * 32 + (ln >> 4) * 8;
        const float* wr = W2 + (size_t)n * HID + k0;
        uint4 v;
        v.x = bbits(wr[0]) | ((unsigned)bbits(wr[1]) << 16);
        v.y = bbits(wr[2]) | ((unsigned)bbits(wr[3]) << 16);
        v.z = bbits(wr[4]) | ((unsigned)bbits(wr[5]) << 16);
        v.w = bbits(wr[6]) | ((unsigned)bbits(wr[7]) << 16);
        *reinterpret_cast<uint4*>(bfr + idx * 16) = v;
    }
    __syncthreads();

    const int ntiles = (E + 63) >> 6;
    for (int tile = blockIdx.x; tile < ntiles; tile += gridDim.x) {
        int e0 = tile << 6;
        for (int idx = tid; idx < 1024; idx += 256) {
            int m = idx >> 8;
            int s = (idx >> 6) & 3, ln = idx & 63;
            int row = m * 16 + (ln & 15);
            int e = e0 + row;
            int k0 = s * 32 + (ln >> 4) * 8;
            uint4 v = make_uint4(0, 0, 0, 0);
            if (e < E) {
                int sn = src[e];
                uint4 a = *reinterpret_cast<const uint4*>(mnb + (size_t)sn * HID + k0);
                uint4 b = *reinterpret_cast<const uint4*>(h + (size_t)(e ^ 1) * HID + k0);
                v.x = pksub(a.x, b.x);
                v.y = pksub(a.y, b.y);
                v.z = pksub(a.z, b.z);
                v.w = pksub(a.w, b.w);
            }
            *reinterpret_cast<uint4*>(afr + ((m * 4 + s) * 64 + ln) * 16) = v;
        }
        // h0 preload in D layout (independent of LDS; overlaps with MFMA)
        u16 h0r[8][4];
        {
            int rbase = e0 + w * 16 + (l >> 4) * 4;
            int cbase = l & 15;
#pragma unroll
            for (int t = 0; t < 8; ++t)
#pragma unroll
                for (int r = 0; r < 4; ++r)
                    h0r[t][r] = h0[(size_t)(rbase + r) * HID + t * 16 + cbase];
        }
        __syncthreads();

        v4f acc[8];
#pragma unroll
        for (int t = 0; t < 8; ++t) acc[t] = (v4f){0.f, 0.f, 0.f, 0.f};
#pragma unroll
        for (int s = 0; s < 4; ++s) {
            short8 af = *reinterpret_cast<short8*>(afr + ((w * 4 + s) * 64 + l) * 16);
#pragma unroll
            for (int t = 0; t < 8; ++t) {
                short8 bv = *reinterpret_cast<short8*>(bfr + ((s * 8 + t) * 64 + l) * 16);
                acc[t] = __builtin_amdgcn_mfma_f32_16x16x32_bf16(af, bv, acc[t], 0, 0, 0);
            }
        }
        char* wb = afr + w * 4096;
#pragma unroll
        for (int t = 0; t < 8; ++t)
#pragma unroll
            for (int r = 0; r < 4; ++r) {
                int row = (l >> 4) * 4 + r;
                int cb = (t * 16 + (l & 15)) * 2;
                *reinterpret_cast<u16*>(wb + row * 256 + (cb ^ ((row & 7) << 4))) =
                    bbits(fmaxf(acc[t][r] + u2f(h0r[t][r]), 0.f));
            }
#pragma unroll
        for (int p = 0; p < 4; ++p) {
            int row = l >> 2, q = l & 3;
            int off = q * 16 + p * 64;
            uint4 v = *reinterpret_cast<uint4*>(wb + row * 256 + (off ^ ((row & 7) << 4)));
            int e = e0 + w * 16 + row;
            if (e < E)
                *reinterpret_cast<uint4*>((char*)(h + (size_t)e * HID) + off) = v;
        }
        __syncthreads();
    }
}

// ---------------- MFMA node MLP + fused run-merged mean-pool ----------------
// z[n] = [xb[n] (136, bf16) || mnb[n] (128, bf16)] padded to K=288
// D = relu(z * W3' + b3); sums[batch[n]] += D rows (run-merged atomics)
__global__ void k_nodem(const u16* __restrict__ xb, const u16* __restrict__ mnb,
                        const float* __restrict__ W3, const float* __restrict__ b3,
                        const int* __restrict__ batch, float* __restrict__ sums, int N) {
    __shared__ __align__(16) char bfr[36864];     // 36 frags (s*4+t) x 1024 B
    const int tid = threadIdx.x, l = tid & 63, w = tid >> 6;
    const int y = blockIdx.y;                     // output-channel half

    for (int idx = tid; idx < 36 * 64; idx += 256) {
        int f = idx >> 6, ln = idx & 63;
        int s = f >> 2, t = f & 3;
        int j = y * 64 + t * 16 + (ln & 15);      // output channel
        int k0 = s * 32 + (ln >> 4) * 8;
        const float* wr = W3 + (size_t)j * 261;
        u16 u[8];
#pragma unroll
        for (int i = 0; i < 8; ++i) {
            int p = k0 + i;
            float v = 0.f;
            if (p < FDIM) v = wr[p];
            else if (p >= 136 && p < 264) v = wr[p - 3];
            u[i] = bbits(v);
        }
        uint4 v;
        v.x = u[0] | ((unsigned)u[1] << 16);
        v.y = u[2] | ((unsigned)u[3] << 16);
        v.z = u[4] | ((unsigned)u[5] << 16);
        v.w = u[6] | ((unsigned)u[7] << 16);
        *reinterpret_cast<uint4*>(bfr + idx * 16) = v;
    }
    __syncthreads();

    float b3v[4];
#pragma unroll
    for (int t = 0; t < 4; ++t) b3v[t] = b3[y * 64 + t * 16 + (l & 15)];

    const int arow = l & 15;                      // A row within wave tile
    const int k0a = (l >> 4) * 8;                 // A k-chunk base (within s*32)
    const int ntiles = (N + 63) >> 6;
    for (int tile = blockIdx.x; tile < ntiles; tile += gridDim.x) {
        int n0 = tile << 6;
        int n_a = n0 + w * 16 + arow;
        bool okA = n_a < N;
        v4f acc[4];
#pragma unroll
        for (int t = 0; t < 4; ++t) acc[t] = (v4f){0.f, 0.f, 0.f, 0.f};
#pragma unroll
        for (int s = 0; s < 9; ++s) {
            int p = s * 32 + k0a;
            uint4 av = make_uint4(0, 0, 0, 0);
            if (okA) {
                if (p < 136)       av = *reinterpret_cast<const uint4*>(xb + (size_t)n_a * 136 + p);
                else if (p < 264)  av = *reinterpret_cast<const uint4*>(mnb + (size_t)n_a * HID + (p - 136));
            }
            short8 af = *reinterpret_cast<short8*>(&av);
#pragma unroll
            for (int t = 0; t < 4; ++t) {
                short8 bv = *reinterpret_cast<short8*>(bfr + ((s * 4 + t) * 64 + l) * 16);
                acc[t] = __builtin_amdgcn_mfma_f32_16x16x32_bf16(af, bv, acc[t], 0, 0, 0);
            }
        }
        // epilogue: relu + run-merged pooling atomics (batch sorted)
        int rbase = n0 + w * 16 + (l >> 4) * 4;
        int gv[4];
#pragma unroll
        for (int r = 0; r < 4; ++r) gv[r] = (rbase + r < N) ? batch[rbase + r] : -1;
#pragma unroll
        for (int t = 0; t < 4; ++t) {
            int j = y * 64 + t * 16 + (l & 15);
            float run = 0.f;
            int gp = gv[0];
#pragma unroll
            for (int r = 0; r < 4; ++r) {
                int g = gv[r];
                if (g != gp) {
                    if (gp >= 0) atomicAdd(&sums[(size_t)gp * HID + j], run);
                    run = 0.f;
                    gp = g;
                }
                if (g >= 0) run += fmaxf(acc[t][r] + b3v[t], 0.f);
            }
            if (gp >= 0) atomicAdd(&sums[(size_t)gp * HID + j], run);
        }
    }
}

__global__ void k_out(const float* __restrict__ sums, const float* __restrict__ counts,
                      const float* __restrict__ Wfc, const float* __restrict__ bfc,
                      float* __restrict__ out, int G) {
    __shared__ float pooled[HID];
    const int g = blockIdx.x, tid = threadIdx.x;  // 64 threads
    float inv = 1.0f / fmaxf(counts[g], 1.0f);
    pooled[tid] = sums[(size_t)g * HID + tid] * inv;
    pooled[tid + 64] = sums[(size_t)g * HID + tid + 64] * inv;
    __syncthreads();
    float acc = bfc[tid];
#pragma unroll
    for (int k = 0; k < HID; ++k) acc += Wfc[tid * HID + k] * pooled[k];
    out[(size_t)g * 64 + tid] = tanhf(acc);
}

extern "C" void kernel_launch(void* const* d_in, const int* in_sizes, int n_in,
                              void* d_out, int out_size, void* d_ws, size_t ws_size,
                              hipStream_t stream) {
    const float* x     = (const float*)d_in[0];
    const int*   ei    = (const int*)d_in[1];
    const float* eattr = (const float*)d_in[3];
    const int*   batch = (const int*)d_in[4];
    const float* W1    = (const float*)d_in[6];
    const float* W2    = (const float*)d_in[7];
    const float* W3    = (const float*)d_in[8];
    const float* b3    = (const float*)d_in[9];
    const float* Wfc   = (const float*)d_in[10];
    const float* bfc   = (const float*)d_in[11];
    float* out = (float*)d_out;
    (void)n_in; (void)ws_size;

    const int N = in_sizes[0] / FDIM;
    const int E = in_sizes[3];
    const int G = out_size / 64;
    const int* src = ei;
    const int* dst = ei + E;

    char* ws = (char*)d_ws;
    size_t o = 0;
    u16* h   = (u16*)(ws + o); o += (size_t)E * HID * 2;
    u16* h0  = (u16*)(ws + o); o += (size_t)E * HID * 2;
    u16* xb  = (u16*)(ws + o); o += (size_t)N * 136 * 2;
    u16* mnb = (u16*)(ws + o); o += (size_t)N * HID * 2;
    size_t o_zero = o;
    float* sums   = (float*)(ws + o); o += (size_t)G * HID * 4;
    float* counts = (float*)(ws + o); o += (size_t)G * 4;
    int* deg    = (int*)(ws + o); o += (size_t)N * 4;
    int* cursor = (int*)(ws + o); o += (size_t)N * 4;
    size_t zero_n = (o - o_zero) / 4;
    int* offs   = (int*)(ws + o); o += (size_t)N * 4;
    int* csr    = (int*)(ws + o); o += (size_t)E * 4;
    int* bsum   = (int*)(ws + o); o += 256 * 4;

    const int eGrid = (E + 255) / 256;
    const int nGrid = (N + 255) / 256;
    const int nbScan = (N + 1023) / 1024;

    k_zero<<<512, 256, 0, stream>>>((float*)(ws + o_zero), (long long)zero_n);
    k_cast<<<2048, 256, 0, stream>>>(x, xb, N);

    k_hist<<<eGrid, 256, 0, stream>>>(dst, deg, E);
    k_scanA<<<nbScan, 256, 0, stream>>>(deg, offs, bsum, N);
    k_scanB<<<1, 256, 0, stream>>>(bsum, nbScan);
    k_scanC<<<nGrid, 256, 0, stream>>>(offs, bsum, N);
    k_fill<<<eGrid, 256, 0, stream>>>(dst, offs, cursor, csr, E);
    k_counts<<<(G + 255) / 256, 256, 0, stream>>>(batch, counts, N, G);

    k_h0m<<<2048, 256, 0, stream>>>(xb, src, eattr, W1, h, h0, E);

    k_gather<<<2048, 256, 0, stream>>>(h, csr, offs, deg, mnb, N);
    k_updm<<<2048, 256, 0, stream>>>(src, mnb, h0, h, W2, E);

    k_gather<<<2048, 256, 0, stream>>>(h, csr, offs, deg, mnb, N);
    k_updm<<<2048, 256, 0, stream>>>(src, mnb, h0, h, W2, E);

    k_gather<<<2048, 256, 0, stream>>>(h, csr, offs, deg, mnb, N);

    k_nodem<<<dim3(512, 2), 256, 0, stream>>>(xb, mnb, W3, b3, batch, sums, N);
    k_out<<<G, 64, 0, stream>>>(sums, counts, Wfc, bfc, out, G);
}

// Round 6
// 536.241 us; speedup vs baseline: 6.9823x; 1.2843x over previous
//
#include <hip/hip_runtime.h>
#include <hip/hip_bf16.h>

#define HID 128
#define FDIM 133

typedef __hip_bfloat16 bf16;
typedef unsigned short u16;
typedef __attribute__((ext_vector_type(8))) short short8;
typedef __attribute__((ext_vector_type(4))) float v4f;

__device__ __forceinline__ u16 bbits(float v) {
    union { bf16 b; u16 u; } cv; cv.b = __float2bfloat16(v); return cv.u;
}
__device__ __forceinline__ float lo16(unsigned u) { return __uint_as_float(u << 16); }
__device__ __forceinline__ float hi16(unsigned u) { return __uint_as_float(u & 0xffff0000u); }
__device__ __forceinline__ float u2f(u16 u) { return __uint_as_float((unsigned)u << 16); }
__device__ __forceinline__ unsigned pksub(unsigned a, unsigned b) {
    float lo = lo16(a) - lo16(b);
    float hi = hi16(a) - hi16(b);
    return (unsigned)bbits(lo) | ((unsigned)bbits(hi) << 16);
}

__global__ void k_zero(float* __restrict__ p, long long n) {
    long long i = (long long)blockIdx.x * blockDim.x + threadIdx.x;
    long long st = (long long)gridDim.x * blockDim.x;
    for (; i < n; i += st) p[i] = 0.f;
}

// xb[n][136] = bf16(x[n][0..132]), 0 pad for 133..135
__global__ void k_cast(const float* __restrict__ x, u16* __restrict__ xb, int N) {
    int i = blockIdx.x * blockDim.x + threadIdx.x;
    int st = gridDim.x * blockDim.x;
    int total = N * 136;
    for (; i < total; i += st) {
        int n = i / 136, k = i - n * 136;
        float v = (k < FDIM) ? x[(size_t)n * FDIM + k] : 0.f;
        xb[i] = bbits(v);
    }
}

// ---------------- CSR build (incoming edges per dst) ----------------
__global__ void k_hist(const int* __restrict__ dst, int* __restrict__ deg, int E) {
    int i = blockIdx.x * blockDim.x + threadIdx.x;
    if (i < E) atomicAdd(&deg[dst[i]], 1);
}

__global__ void k_scanA(const int* __restrict__ deg, int* __restrict__ offs,
                        int* __restrict__ bsum, int N) {
    __shared__ int sh[256];
    int t = threadIdx.x;
    int base = blockIdx.x * 1024 + t * 4;
    int d0 = (base + 0 < N) ? deg[base + 0] : 0;
    int d1 = (base + 1 < N) ? deg[base + 1] : 0;
    int d2 = (base + 2 < N) ? deg[base + 2] : 0;
    int d3 = (base + 3 < N) ? deg[base + 3] : 0;
    sh[t] = d0 + d1 + d2 + d3;
    __syncthreads();
    for (int off = 1; off < 256; off <<= 1) {
        int v = (t >= off) ? sh[t - off] : 0;
        __syncthreads();
        sh[t] += v;
        __syncthreads();
    }
    int o = (t > 0) ? sh[t - 1] : 0;
    if (t == 255) bsum[blockIdx.x] = sh[255];
    if (base + 0 < N) offs[base + 0] = o; o += d0;
    if (base + 1 < N) offs[base + 1] = o; o += d1;
    if (base + 2 < N) offs[base + 2] = o; o += d2;
    if (base + 3 < N) offs[base + 3] = o;
}

__global__ void k_scanB(int* __restrict__ bsum, int nb) {
    __shared__ int sh[256];
    int t = threadIdx.x;
    sh[t] = (t < nb) ? bsum[t] : 0;
    __syncthreads();
    for (int off = 1; off < 256; off <<= 1) {
        int v = (t >= off) ? sh[t - off] : 0;
        __syncthreads();
        sh[t] += v;
        __syncthreads();
    }
    if (t < nb) bsum[t] = (t > 0) ? sh[t - 1] : 0;
}

__global__ void k_scanC(int* __restrict__ offs, const int* __restrict__ bsum, int N) {
    int i = blockIdx.x * blockDim.x + threadIdx.x;
    if (i < N) offs[i] += bsum[i >> 10];
}

__global__ void k_fill(const int* __restrict__ dst, const int* __restrict__ offs,
                       int* __restrict__ cursor, int* __restrict__ csr, int E) {
    int e = blockIdx.x * blockDim.x + threadIdx.x;
    if (e < E) {
        int d = dst[e];
        int p = offs[d] + atomicAdd(&cursor[d], 1);
        csr[p] = e;
    }
}

// starts[g] = lower_bound(batch, g) for g in [0, G]  (batch sorted)
__global__ void k_starts(const int* __restrict__ batch, int* __restrict__ starts,
                         int N, int G) {
    int g = blockIdx.x * blockDim.x + threadIdx.x;
    if (g > G) return;
    int lo = 0, hi = N;
    while (lo < hi) { int mid = (lo + hi) >> 1; if (batch[mid] < g) lo = mid + 1; else hi = mid; }
    starts[g] = lo;
}

// mnb[n] (bf16) = sum of h rows over incoming edges (one wave per node, 4-deep ILP)
__global__ void k_gather(const u16* __restrict__ h, const int* __restrict__ csr,
                         const int* __restrict__ offs, const int* __restrict__ deg,
                         u16* __restrict__ mnb, int N) {
    int gw = (blockIdx.x * blockDim.x + threadIdx.x) >> 6;
    int lane = threadIdx.x & 63;
    int nw = (gridDim.x * blockDim.x) >> 6;
    for (int n = gw; n < N; n += nw) {
        int s = offs[n], d = deg[n];
        float a0 = 0.f, a1 = 0.f;
        int i = 0;
        for (; i + 4 <= d; i += 4) {
            int ea = csr[s + i], eb = csr[s + i + 1], ec = csr[s + i + 2], ed = csr[s + i + 3];
            unsigned ua = *reinterpret_cast<const unsigned*>(h + (size_t)ea * HID + 2 * lane);
            unsigned ub = *reinterpret_cast<const unsigned*>(h + (size_t)eb * HID + 2 * lane);
            unsigned uc = *reinterpret_cast<const unsigned*>(h + (size_t)ec * HID + 2 * lane);
            unsigned ud = *reinterpret_cast<const unsigned*>(h + (size_t)ed * HID + 2 * lane);
            a0 += lo16(ua) + lo16(ub) + lo16(uc) + lo16(ud);
            a1 += hi16(ua) + hi16(ub) + hi16(uc) + hi16(ud);
        }
        for (; i < d; ++i) {
            int e = csr[s + i];
            unsigned u = *reinterpret_cast<const unsigned*>(h + (size_t)e * HID + 2 * lane);
            a0 += lo16(u);
            a1 += hi16(u);
        }
        *reinterpret_cast<unsigned*>(mnb + (size_t)n * HID + 2 * lane) =
            (unsigned)bbits(a0) | ((unsigned)bbits(a1) << 16);
    }
}

// ---------------- MFMA edge kernels ----------------
// h0[e][j] = relu(sum_k W1[j][k] * [xb[src[e]], eattr]), 64-edge tiles, K=160
__global__ void k_h0m(const u16* __restrict__ xb, const int* __restrict__ src,
                      const float* __restrict__ eattr, const float* __restrict__ W1,
                      u16* __restrict__ h0, int E) {
    __shared__ __align__(16) char lds[61440];
    char* bfr = lds;               // 40 frags (s*8+t) x 1024 B
    char* afr = lds + 40960;       // 20 frags (m*5+s) x 1024 B
    const int tid = threadIdx.x, l = tid & 63, w = tid >> 6;

    for (int idx = tid; idx < 40 * 64; idx += 256) {
        int f = idx >> 6, ln = idx & 63;
        int s = f >> 3, t = f & 7;
        int n = t * 16 + (ln & 15);
        int k0 = s * 32 + (ln >> 4) * 8;
        u16 u[8];
#pragma unroll
        for (int i = 0; i < 8; ++i) {
            int k = k0 + i;
            u[i] = (k < FDIM + 1) ? bbits(W1[n * (FDIM + 1) + k]) : (u16)0;
        }
        uint4 v;
        v.x = u[0] | ((unsigned)u[1] << 16);
        v.y = u[2] | ((unsigned)u[3] << 16);
        v.z = u[4] | ((unsigned)u[5] << 16);
        v.w = u[6] | ((unsigned)u[7] << 16);
        *reinterpret_cast<uint4*>(bfr + idx * 16) = v;
    }
    __syncthreads();

    const int ntiles = (E + 63) >> 6;
    for (int tile = blockIdx.x; tile < ntiles; tile += gridDim.x) {
        int e0 = tile << 6;
        for (int idx = tid; idx < 1280; idx += 256) {
            int m = idx / 320;
            int rem = idx - m * 320;
            int s = rem >> 6, ln = rem & 63;
            int row = m * 16 + (ln & 15);
            int e = e0 + row;
            int k0 = s * 32 + (ln >> 4) * 8;
            uint4 v = make_uint4(0, 0, 0, 0);
            if (e < E && k0 < 136) {
                int sn = src[e];
                v = *reinterpret_cast<const uint4*>(xb + (size_t)sn * 136 + k0);
                if (k0 == 128)  // inject eattr at k=133 (elem 5 -> hi half of .z)
                    v.z = (v.z & 0xFFFFu) | ((unsigned)bbits(eattr[e]) << 16);
            }
            *reinterpret_cast<uint4*>(afr + ((m * 5 + s) * 64 + ln) * 16) = v;
        }
        __syncthreads();

        v4f acc[8];
#pragma unroll
        for (int t = 0; t < 8; ++t) acc[t] = (v4f){0.f, 0.f, 0.f, 0.f};
#pragma unroll
        for (int s = 0; s < 5; ++s) {
            short8 af = *reinterpret_cast<short8*>(afr + ((w * 5 + s) * 64 + l) * 16);
#pragma unroll
            for (int t = 0; t < 8; ++t) {
                short8 bv = *reinterpret_cast<short8*>(bfr + ((s * 8 + t) * 64 + l) * 16);
                acc[t] = __builtin_amdgcn_mfma_f32_16x16x32_bf16(af, bv, acc[t], 0, 0, 0);
            }
        }
        // bounce D through wave-private LDS (reuses this wave's afrag region)
        char* wb = afr + w * 5120;
#pragma unroll
        for (int t = 0; t < 8; ++t)
#pragma unroll
            for (int r = 0; r < 4; ++r) {
                int row = (l >> 4) * 4 + r;
                int cb = (t * 16 + (l & 15)) * 2;
                *reinterpret_cast<u16*>(wb + row * 256 + (cb ^ ((row & 7) << 4))) =
                    bbits(fmaxf(acc[t][r], 0.f));
            }
#pragma unroll
        for (int p = 0; p < 4; ++p) {
            int row = l >> 2, q = l & 3;
            int off = q * 16 + p * 64;
            uint4 v = *reinterpret_cast<uint4*>(wb + row * 256 + (off ^ ((row & 7) << 4)));
            int e = e0 + w * 16 + row;
            if (e < E)
                *reinterpret_cast<uint4*>((char*)(h0 + (size_t)e * HID) + off) = v;
        }
        __syncthreads();
    }
}

// hout[e] = relu(h0[e] + W2*(mnb[src[e]] - hin[e^1])), 64-edge tiles, K=128
// hin may equal h0 (iteration 1) or hout (in-place, iteration 2).
__global__ void k_updm(const int* __restrict__ src, const u16* __restrict__ mnb,
                       const u16* __restrict__ h0, const u16* hin, u16* hout,
                       const float* __restrict__ W2, int E) {
    __shared__ __align__(16) char lds[49152];
    char* bfr = lds;               // 32 frags (s*8+t) x 1024 B
    char* afr = lds + 32768;       // 16 frags (m*4+s) x 1024 B
    const int tid = threadIdx.x, l = tid & 63, w = tid >> 6;

    for (int idx = tid; idx < 32 * 64; idx += 256) {
        int f = idx >> 6, ln = idx & 63;
        int s = f >> 3, t = f & 7;
        int n = t * 16 + (ln & 15);
        int k0 = s * 32 + (ln >> 4) * 8;
        const float* wr = W2 + (size_t)n * HID + k0;
        uint4 v;
        v.x = bbits(wr[0]) | ((unsigned)bbits(wr[1]) << 16);
        v.y = bbits(wr[2]) | ((unsigned)bbits(wr[3]) << 16);
        v.z = bbits(wr[4]) | ((unsigned)bbits(wr[5]) << 16);
        v.w = bbits(wr[6]) | ((unsigned)bbits(wr[7]) << 16);
        *reinterpret_cast<uint4*>(bfr + idx * 16) = v;
    }
    __syncthreads();

    const int ntiles = (E + 63) >> 6;
    for (int tile = blockIdx.x; tile < ntiles; tile += gridDim.x) {
        int e0 = tile << 6;
        for (int idx = tid; idx < 1024; idx += 256) {
            int m = idx >> 8;
            int s = (idx >> 6) & 3, ln = idx & 63;
            int row = m * 16 + (ln & 15);
            int e = e0 + row;
            int k0 = s * 32 + (ln >> 4) * 8;
            uint4 v = make_uint4(0, 0, 0, 0);
            if (e < E) {
                int sn = src[e];
                uint4 a = *reinterpret_cast<const uint4*>(mnb + (size_t)sn * HID + k0);
                uint4 b = *reinterpret_cast<const uint4*>(hin + (size_t)(e ^ 1) * HID + k0);
                v.x = pksub(a.x, b.x);
                v.y = pksub(a.y, b.y);
                v.z = pksub(a.z, b.z);
                v.w = pksub(a.w, b.w);
            }
            *reinterpret_cast<uint4*>(afr + ((m * 4 + s) * 64 + ln) * 16) = v;
        }
        // h0 preload in D layout (independent of LDS; overlaps with MFMA)
        u16 h0r[8][4];
        {
            int rbase = e0 + w * 16 + (l >> 4) * 4;
            int cbase = l & 15;
#pragma unroll
            for (int t = 0; t < 8; ++t)
#pragma unroll
                for (int r = 0; r < 4; ++r)
                    h0r[t][r] = h0[(size_t)(rbase + r) * HID + t * 16 + cbase];
        }
        __syncthreads();

        v4f acc[8];
#pragma unroll
        for (int t = 0; t < 8; ++t) acc[t] = (v4f){0.f, 0.f, 0.f, 0.f};
#pragma unroll
        for (int s = 0; s < 4; ++s) {
            short8 af = *reinterpret_cast<short8*>(afr + ((w * 4 + s) * 64 + l) * 16);
#pragma unroll
            for (int t = 0; t < 8; ++t) {
                short8 bv = *reinterpret_cast<short8*>(bfr + ((s * 8 + t) * 64 + l) * 16);
                acc[t] = __builtin_amdgcn_mfma_f32_16x16x32_bf16(af, bv, acc[t], 0, 0, 0);
            }
        }
        char* wb = afr + w * 4096;
#pragma unroll
        for (int t = 0; t < 8; ++t)
#pragma unroll
            for (int r = 0; r < 4; ++r) {
                int row = (l >> 4) * 4 + r;
                int cb = (t * 16 + (l & 15)) * 2;
                *reinterpret_cast<u16*>(wb + row * 256 + (cb ^ ((row & 7) << 4))) =
                    bbits(fmaxf(acc[t][r] + u2f(h0r[t][r]), 0.f));
            }
#pragma unroll
        for (int p = 0; p < 4; ++p) {
            int row = l >> 2, q = l & 3;
            int off = q * 16 + p * 64;
            uint4 v = *reinterpret_cast<uint4*>(wb + row * 256 + (off ^ ((row & 7) << 4)));
            int e = e0 + w * 16 + row;
            if (e < E)
                *reinterpret_cast<uint4*>((char*)(hout + (size_t)e * HID) + off) = v;
        }
        __syncthreads();
    }
}

// ---------------- MFMA node MLP -> bf16 node_attr (no atomics) ----------------
// z[n] = [xb[n] (136, bf16) || mnb[n] (128, bf16)] padded to K=288
// na[n][y*64 .. y*64+63] = relu(z * W3' + b3)
__global__ void k_nodem(const u16* __restrict__ xb, const u16* __restrict__ mnb,
                        const float* __restrict__ W3, const float* __restrict__ b3,
                        u16* __restrict__ na, int N) {
    __shared__ __align__(16) char lds[45056];
    char* bfr = lds;                              // 36 frags (s*4+t) x 1024 B
    char* bounce = lds + 36864;                   // 4 waves x 2048 B
    const int tid = threadIdx.x, l = tid & 63, w = tid >> 6;
    const int y = blockIdx.y;                     // output-channel half

    for (int idx = tid; idx < 36 * 64; idx += 256) {
        int f = idx >> 6, ln = idx & 63;
        int s = f >> 2, t = f & 3;
        int j = y * 64 + t * 16 + (ln & 15);      // output channel
        int k0 = s * 32 + (ln >> 4) * 8;
        const float* wr = W3 + (size_t)j * 261;
        u16 u[8];
#pragma unroll
        for (int i = 0; i < 8; ++i) {
            int p = k0 + i;
            float v = 0.f;
            if (p < FDIM) v = wr[p];
            else if (p >= 136 && p < 264) v = wr[p - 3];
            u[i] = bbits(v);
        }
        uint4 v;
        v.x = u[0] | ((unsigned)u[1] << 16);
        v.y = u[2] | ((unsigned)u[3] << 16);
        v.z = u[4] | ((unsigned)u[5] << 16);
        v.w = u[6] | ((unsigned)u[7] << 16);
        *reinterpret_cast<uint4*>(bfr + idx * 16) = v;
    }
    __syncthreads();

    float b3v[4];
#pragma unroll
    for (int t = 0; t < 4; ++t) b3v[t] = b3[y * 64 + t * 16 + (l & 15)];

    const int arow = l & 15;
    const int k0a = (l >> 4) * 8;
    const int ntiles = (N + 63) >> 6;
    for (int tile = blockIdx.x; tile < ntiles; tile += gridDim.x) {
        int n0 = tile << 6;
        int n_a = n0 + w * 16 + arow;
        bool okA = n_a < N;
        v4f acc[4];
#pragma unroll
        for (int t = 0; t < 4; ++t) acc[t] = (v4f){0.f, 0.f, 0.f, 0.f};
#pragma unroll
        for (int s = 0; s < 9; ++s) {
            int p = s * 32 + k0a;
            uint4 av = make_uint4(0, 0, 0, 0);
            if (okA) {
                if (p < 136)       av = *reinterpret_cast<const uint4*>(xb + (size_t)n_a * 136 + p);
                else if (p < 264)  av = *reinterpret_cast<const uint4*>(mnb + (size_t)n_a * HID + (p - 136));
            }
            short8 af = *reinterpret_cast<short8*>(&av);
#pragma unroll
            for (int t = 0; t < 4; ++t) {
                short8 bv = *reinterpret_cast<short8*>(bfr + ((s * 4 + t) * 64 + l) * 16);
                acc[t] = __builtin_amdgcn_mfma_f32_16x16x32_bf16(af, bv, acc[t], 0, 0, 0);
            }
        }
        // epilogue: relu -> wave-private LDS bounce -> coalesced bf16 stores
        char* wb = bounce + w * 2048;             // 16 rows x 128 B
#pragma unroll
        for (int t = 0; t < 4; ++t)
#pragma unroll
            for (int r = 0; r < 4; ++r) {
                int row = (l >> 4) * 4 + r;
                int cb = (t * 16 + (l & 15)) * 2;
                *reinterpret_cast<u16*>(wb + row * 128 + (cb ^ ((row & 7) << 4))) =
                    bbits(fmaxf(acc[t][r] + b3v[t], 0.f));
            }
#pragma unroll
        for (int p = 0; p < 2; ++p) {
            int row = (l >> 3) + p * 8;           // 0..15
            int ch = l & 7;
            uint4 v = *reinterpret_cast<uint4*>(wb + row * 128 + ((ch * 16) ^ ((row & 7) << 4)));
            int n = n0 + w * 16 + row;
            if (n < N)
                *reinterpret_cast<uint4*>((char*)(na + (size_t)n * HID) + y * 128 + ch * 16) = v;
        }
    }
}

// pooled[g] = mean over rows [starts[g], starts[g+1]) of na  (no atomics)
__global__ void k_pool(const u16* __restrict__ na, const int* __restrict__ starts,
                       float* __restrict__ pooled, int G) {
    __shared__ float red[256];
    const int g = blockIdx.x, tid = threadIdx.x;  // 256 threads
    const int ch = tid & 127, half = tid >> 7;
    int s = starts[g], e = starts[g + 1];
    float acc = 0.f;
    int n = s + half;
    for (; n + 2 < e; n += 4) {                   // 2 rows in flight per thread-group
        float v0 = u2f(na[(size_t)n * HID + ch]);
        float v1 = u2f(na[(size_t)(n + 2) * HID + ch]);
        acc += v0 + v1;
    }
    for (; n < e; n += 2) acc += u2f(na[(size_t)n * HID + ch]);
    red[tid] = acc;
    __syncthreads();
    if (half == 0) {
        float v = red[tid] + red[tid + 128];
        float cnt = (float)(e - s);
        pooled[(size_t)g * HID + ch] = v / fmaxf(cnt, 1.f);
    }
}

__global__ void k_out(const float* __restrict__ pooled, const float* __restrict__ Wfc,
                      const float* __restrict__ bfc, float* __restrict__ out, int G) {
    __shared__ float pl[HID];
    const int g = blockIdx.x, tid = threadIdx.x;  // 64 threads
    pl[tid] = pooled[(size_t)g * HID + tid];
    pl[tid + 64] = pooled[(size_t)g * HID + tid + 64];
    __syncthreads();
    float acc = bfc[tid];
#pragma unroll
    for (int k = 0; k < HID; ++k) acc += Wfc[tid * HID + k] * pl[k];
    out[(size_t)g * 64 + tid] = tanhf(acc);
}

extern "C" void kernel_launch(void* const* d_in, const int* in_sizes, int n_in,
                              void* d_out, int out_size, void* d_ws, size_t ws_size,
                              hipStream_t stream) {
    const float* x     = (const float*)d_in[0];
    const int*   ei    = (const int*)d_in[1];
    const float* eattr = (const float*)d_in[3];
    const int*   batch = (const int*)d_in[4];
    const float* W1    = (const float*)d_in[6];
    const float* W2    = (const float*)d_in[7];
    const float* W3    = (const float*)d_in[8];
    const float* b3    = (const float*)d_in[9];
    const float* Wfc   = (const float*)d_in[10];
    const float* bfc   = (const float*)d_in[11];
    float* out = (float*)d_out;
    (void)n_in; (void)ws_size;

    const int N = in_sizes[0] / FDIM;
    const int E = in_sizes[3];
    const int G = out_size / 64;
    const int* src = ei;
    const int* dst = ei + E;

    char* ws = (char*)d_ws;
    size_t o = 0;
    u16* h   = (u16*)(ws + o); o += (size_t)E * HID * 2;
    u16* h0  = (u16*)(ws + o); o += (size_t)E * HID * 2;   // reused as na after updm#2
    u16* xb  = (u16*)(ws + o); o += (size_t)N * 136 * 2;
    u16* mnb = (u16*)(ws + o); o += (size_t)N * HID * 2;
    float* pooled = (float*)(ws + o); o += (size_t)G * HID * 4;
    int* starts = (int*)(ws + o); o += (size_t)(G + 1) * 4;
    size_t o_zero = o;
    int* deg    = (int*)(ws + o); o += (size_t)N * 4;
    int* cursor = (int*)(ws + o); o += (size_t)N * 4;
    size_t zero_n = (o - o_zero) / 4;
    int* offs   = (int*)(ws + o); o += (size_t)N * 4;
    int* csr    = (int*)(ws + o); o += (size_t)E * 4;
    int* bsum   = (int*)(ws + o); o += 256 * 4;
    u16* na = h0;   // h0 dead after k_updm #2; N*256 B fits inside E*256 B

    const int eGrid = (E + 255) / 256;
    const int nGrid = (N + 255) / 256;
    const int nbScan = (N + 1023) / 1024;

    k_zero<<<512, 256, 0, stream>>>((float*)(ws + o_zero), (long long)zero_n);
    k_cast<<<2048, 256, 0, stream>>>(x, xb, N);

    k_hist<<<eGrid, 256, 0, stream>>>(dst, deg, E);
    k_scanA<<<nbScan, 256, 0, stream>>>(deg, offs, bsum, N);
    k_scanB<<<1, 256, 0, stream>>>(bsum, nbScan);
    k_scanC<<<nGrid, 256, 0, stream>>>(offs, bsum, N);
    k_fill<<<eGrid, 256, 0, stream>>>(dst, offs, cursor, csr, E);
    k_starts<<<(G + 256) / 256, 256, 0, stream>>>(batch, starts, N, G);

    // h0 = relu(W1*[x[src],eattr])   (single write; h == h0 logically at iter 1)
    k_h0m<<<2048, 256, 0, stream>>>(xb, src, eattr, W1, h0, E);

    // iter 1: gather from h0, update reads h0 as both h-in and h0, writes h
    k_gather<<<2048, 256, 0, stream>>>(h0, csr, offs, deg, mnb, N);
    k_updm<<<2048, 256, 0, stream>>>(src, mnb, h0, h0, h, W2, E);

    // iter 2: in-place on h
    k_gather<<<2048, 256, 0, stream>>>(h, csr, offs, deg, mnb, N);
    k_updm<<<2048, 256, 0, stream>>>(src, mnb, h0, h, h, W2, E);

    // final v_msg
    k_gather<<<2048, 256, 0, stream>>>(h, csr, offs, deg, mnb, N);

    // node MLP -> na (bf16), then atomic-free pooling and readout
    k_nodem<<<dim3(512, 2), 256, 0, stream>>>(xb, mnb, W3, b3, na, N);
    k_pool<<<G, 256, 0, stream>>>(na, starts, pooled, G);
    k_out<<<G, 64, 0, stream>>>(pooled, Wfc, bfc, out, G);
}